// Round 1
// baseline (6906.869 us; speedup 1.0000x reference)
//
#include <hip/hip_runtime.h>
#include <hip/hip_bf16.h>
#include <float.h>

// Problem constants
#define BB 8
#define NN 4096
#define KNN 16
#define Dh 128
#define NPTS (BB*NN)          // 32768
#define NP 4                  // points per fused block

// ---------------------------------------------------------------------------
// x = relu(features @ W_embed)   [B*N,3] @ [3,128]
__global__ __launch_bounds__(256) void embed_kernel(
    const float* __restrict__ f, const float* __restrict__ We, float* __restrict__ x) {
  int i = blockIdx.x * 256 + threadIdx.x;          // over NPTS*Dh
  if (i >= NPTS * Dh) return;
  int p = i >> 7, d = i & 127;
  float f0 = f[p*3+0], f1 = f[p*3+1], f2 = f[p*3+2];
  float v = f0 * We[0*Dh + d] + f1 * We[1*Dh + d] + f2 * We[2*Dh + d];
  x[i] = fmaxf(v, 0.f);
}

// ---------------------------------------------------------------------------
// kNN: per-batch pairwise d2 = sq_i + sq_j - 2*dot, keep 16 smallest (indices).
// grid (64, B), block 64. Writes GLOBAL row indices.
__global__ __launch_bounds__(64) void knn_kernel(
    const float* __restrict__ pos, int* __restrict__ idxout) {
  __shared__ float px[NN], py[NN], pz[NN], sq[NN];   // 64 KB
  int b = blockIdx.y;
  const float* pb = pos + (size_t)b * NN * 3;
  for (int i = threadIdx.x; i < NN; i += 64) {
    float X = pb[i*3+0], Y = pb[i*3+1], Z = pb[i*3+2];
    px[i] = X; py[i] = Y; pz[i] = Z;
    sq[i] = X*X + Y*Y + Z*Z;
  }
  __syncthreads();

  int n = blockIdx.x * 64 + threadIdx.x;
  float qx = px[n], qy = py[n], qz = pz[n], qs = sq[n];

  float val[KNN]; int ind[KNN];
  #pragma unroll
  for (int i = 0; i < KNN; i++) { val[i] = FLT_MAX; ind[i] = 0; }
  float cmax = FLT_MAX; int cslot = 0;

  for (int m = 0; m < NN; m++) {
    float dot = qx*px[m] + qy*py[m] + qz*pz[m];
    float d2 = qs + sq[m] - 2.f*dot;
    if (d2 < cmax) {                 // strict <: ties keep earlier index (ref tie-break)
      #pragma unroll
      for (int i = 0; i < KNN; i++) if (i == cslot) { val[i] = d2; ind[i] = m; }
      cmax = val[0]; cslot = 0;
      #pragma unroll
      for (int i = 1; i < KNN; i++) if (val[i] >= cmax) { cmax = val[i]; cslot = i; } // evict latest among ties
    }
  }
  int base = (b*NN + n) * KNN;
  #pragma unroll
  for (int i = 0; i < KNN; i++) idxout[base + i] = b*NN + ind[i];
}

// ---------------------------------------------------------------------------
// k,v GEMM: [NPTS,128] @ [128,128] for Wk (y=0) and Wv (y=1). 32 rows/block.
__global__ __launch_bounds__(128) void kv_kernel(
    const float* __restrict__ x, const float* __restrict__ Wk, const float* __restrict__ Wv,
    float* __restrict__ kout, float* __restrict__ vout) {
  __shared__ float xt[32][Dh];    // 16 KB
  int r0 = blockIdx.x * 32;
  for (int i = threadIdx.x; i < 32*Dh; i += 128) xt[i >> 7][i & 127] = x[(size_t)r0*Dh + i];
  __syncthreads();
  const float* W = blockIdx.y ? Wv : Wk;
  float* out = blockIdx.y ? vout : kout;
  int d = threadIdx.x;
  float acc[32];
  #pragma unroll
  for (int r = 0; r < 32; r++) acc[r] = 0.f;
  for (int c = 0; c < Dh; c += 4) {
    float w0 = W[(c+0)*Dh + d], w1 = W[(c+1)*Dh + d], w2 = W[(c+2)*Dh + d], w3 = W[(c+3)*Dh + d];
    #pragma unroll
    for (int r = 0; r < 32; r++) {
      float4 a = *(const float4*)&xt[r][c];
      acc[r] += a.x*w0 + a.y*w1 + a.z*w2 + a.w*w3;
    }
  }
  #pragma unroll
  for (int r = 0; r < 32; r++) out[(size_t)(r0 + r)*Dh + d] = acc[r];
}

// ---------------------------------------------------------------------------
// Fused per-point transformer block. NP points per block, 128 threads per point.
// Thread d owns output channel d of its point.
#define ACC16(acc, a0, a1, a2, a3, w)                                     \
  acc[0]  += a0.x*(w); acc[1]  += a0.y*(w); acc[2]  += a0.z*(w); acc[3]  += a0.w*(w); \
  acc[4]  += a1.x*(w); acc[5]  += a1.y*(w); acc[6]  += a1.z*(w); acc[7]  += a1.w*(w); \
  acc[8]  += a2.x*(w); acc[9]  += a2.y*(w); acc[10] += a2.z*(w); acc[11] += a2.w*(w); \
  acc[12] += a3.x*(w); acc[13] += a3.y*(w); acc[14] += a3.z*(w); acc[15] += a3.w*(w);

__global__ __launch_bounds__(NP*128) void fused_layer_kernel(
    float* __restrict__ x, const float* __restrict__ kbuf, const float* __restrict__ vbuf,
    const int* __restrict__ idxb, const float* __restrict__ pos,
    const float* __restrict__ Wq, const float* __restrict__ P1, const float* __restrict__ P2,
    const float* __restrict__ G1, const float* __restrict__ G2, const float* __restrict__ Wo) {
  __shared__ float bufA[NP][Dh][KNN];   // channel-major [c][k]: 8 KB per point
  __shared__ float bufB[NP][Dh][KNN];
  __shared__ float xrow[NP][Dh];
  __shared__ float aggS[NP][Dh];
  __shared__ float relS[NP][KNN][3];
  __shared__ int   idxS[NP][KNN];

  int pt = threadIdx.x >> 7;            // waves never straddle pt (wave=64, 128 thr/pt)
  int d  = threadIdx.x & 127;
  int p  = blockIdx.x * NP + pt;        // global point id

  xrow[pt][d] = x[(size_t)p*Dh + d];
  if (d < KNN) {
    int j = idxb[p*KNN + d];
    idxS[pt][d] = j;
    relS[pt][d][0] = pos[p*3+0] - pos[j*3+0];
    relS[pt][d][1] = pos[p*3+1] - pos[j*3+1];
    relS[pt][d][2] = pos[p*3+2] - pos[j*3+2];
  }
  __syncthreads();

  // q_d = (x_row @ Wq)[d]
  float qd = 0.f;
  for (int c = 0; c < Dh; c += 4) {
    float4 xv = *(const float4*)&xrow[pt][c];
    qd += xv.x * Wq[(c+0)*Dh + d];
    qd += xv.y * Wq[(c+1)*Dh + d];
    qd += xv.z * Wq[(c+2)*Dh + d];
    qd += xv.w * Wq[(c+3)*Dh + d];
  }

  // t1 = relu(rel @ P1)  -> bufA[pt][d][k]
  {
    float w0 = P1[0*Dh + d], w1 = P1[1*Dh + d], w2 = P1[2*Dh + d];
    float t[KNN];
    #pragma unroll
    for (int k = 0; k < KNN; k++)
      t[k] = fmaxf(relS[pt][k][0]*w0 + relS[pt][k][1]*w1 + relS[pt][k][2]*w2, 0.f);
    #pragma unroll
    for (int k = 0; k < KNN; k += 4)
      *(float4*)&bufA[pt][d][k] = make_float4(t[k], t[k+1], t[k+2], t[k+3]);
  }
  __syncthreads();

  // delta[k][d] = (t1 @ P2)[k][d]   (kept in regs)
  float dlt[KNN];
  #pragma unroll
  for (int k = 0; k < KNN; k++) dlt[k] = 0.f;
  for (int c = 0; c < Dh; c++) {
    float w = P2[c*Dh + d];
    float4 a0 = *(const float4*)&bufA[pt][c][0];
    float4 a1 = *(const float4*)&bufA[pt][c][4];
    float4 a2 = *(const float4*)&bufA[pt][c][8];
    float4 a3 = *(const float4*)&bufA[pt][c][12];
    ACC16(dlt, a0, a1, a2, a3, w)
  }

  // g = q - kj + delta -> bufB[pt][d][k];  vj kept in regs
  float vjr[KNN], g[KNN];
  #pragma unroll
  for (int k = 0; k < KNN; k++) {
    int j = idxS[pt][k];
    float kk = kbuf[(size_t)j*Dh + d];
    vjr[k] = vbuf[(size_t)j*Dh + d];
    g[k] = qd - kk + dlt[k];
  }
  #pragma unroll
  for (int k = 0; k < KNN; k += 4)
    *(float4*)&bufB[pt][d][k] = make_float4(g[k], g[k+1], g[k+2], g[k+3]);
  __syncthreads();

  // h1 = relu(g @ G1) -> bufA (safe: bufA reads all completed before last sync)
  float acc[KNN];
  #pragma unroll
  for (int k = 0; k < KNN; k++) acc[k] = 0.f;
  for (int c = 0; c < Dh; c++) {
    float w = G1[c*Dh + d];
    float4 a0 = *(const float4*)&bufB[pt][c][0];
    float4 a1 = *(const float4*)&bufB[pt][c][4];
    float4 a2 = *(const float4*)&bufB[pt][c][8];
    float4 a3 = *(const float4*)&bufB[pt][c][12];
    ACC16(acc, a0, a1, a2, a3, w)
  }
  __syncthreads();   // ensure all bufB reads done before overwriting bufA? (bufA!=bufB, but keep ordering for bufA readers below)
  #pragma unroll
  for (int k = 0; k < KNN; k += 4)
    *(float4*)&bufA[pt][d][k] = make_float4(fmaxf(acc[k],0.f), fmaxf(acc[k+1],0.f),
                                            fmaxf(acc[k+2],0.f), fmaxf(acc[k+3],0.f));
  __syncthreads();

  // logits = h1 @ G2 (regs)
  float lg[KNN];
  #pragma unroll
  for (int k = 0; k < KNN; k++) lg[k] = 0.f;
  for (int c = 0; c < Dh; c++) {
    float w = G2[c*Dh + d];
    float4 a0 = *(const float4*)&bufA[pt][c][0];
    float4 a1 = *(const float4*)&bufA[pt][c][4];
    float4 a2 = *(const float4*)&bufA[pt][c][8];
    float4 a3 = *(const float4*)&bufA[pt][c][12];
    ACC16(lg, a0, a1, a2, a3, w)
  }

  // softmax over k (per channel d), then agg_d = sum_k attn*(vj+delta)
  float m = lg[0];
  #pragma unroll
  for (int k = 1; k < KNN; k++) m = fmaxf(m, lg[k]);
  float s = 0.f;
  #pragma unroll
  for (int k = 0; k < KNN; k++) { lg[k] = __expf(lg[k] - m); s += lg[k]; }
  float inv = 1.f / s;
  float aggd = 0.f;
  #pragma unroll
  for (int k = 0; k < KNN; k++) aggd += lg[k] * inv * (vjr[k] + dlt[k]);
  aggS[pt][d] = aggd;
  __syncthreads();

  // x += agg @ Wo
  float r = xrow[pt][d];
  for (int c = 0; c < Dh; c += 4) {
    float4 av = *(const float4*)&aggS[pt][c];
    r += av.x * Wo[(c+0)*Dh + d];
    r += av.y * Wo[(c+1)*Dh + d];
    r += av.z * Wo[(c+2)*Dh + d];
    r += av.w * Wo[(c+3)*Dh + d];
  }
  x[(size_t)p*Dh + d] = r;
}

// ---------------------------------------------------------------------------
// Global max-pool over N, two stages, then classifier head.
__global__ __launch_bounds__(128) void pool_part_kernel(
    const float* __restrict__ x, float* __restrict__ part) {
  int b = blockIdx.y, chunk = blockIdx.x, d = threadIdx.x;
  const float* xb = x + ((size_t)b*NN + chunk*128) * Dh;
  float m = -FLT_MAX;
  for (int n = 0; n < 128; n++) m = fmaxf(m, xb[(size_t)n*Dh + d]);
  part[(b*32 + chunk)*Dh + d] = m;
}

__global__ __launch_bounds__(128) void head_kernel(
    const float* __restrict__ part, const float* __restrict__ W1,
    const float* __restrict__ W2, float* __restrict__ out) {
  int b = blockIdx.x, d = threadIdx.x;
  __shared__ float pooled[Dh], h[Dh];
  float m = -FLT_MAX;
  for (int c = 0; c < 32; c++) m = fmaxf(m, part[(b*32 + c)*Dh + d]);
  pooled[d] = m;
  __syncthreads();
  float acc = 0.f;
  for (int c = 0; c < Dh; c++) acc += pooled[c] * W1[c*Dh + d];
  h[d] = fmaxf(acc, 0.f);
  __syncthreads();
  if (d < 40) {
    float o = 0.f;
    for (int c = 0; c < Dh; c++) o += h[c] * W2[c*40 + d];
    out[b*40 + d] = o;
  }
}

// ---------------------------------------------------------------------------
extern "C" void kernel_launch(void* const* d_in, const int* in_sizes, int n_in,
                              void* d_out, int out_size, void* d_ws, size_t ws_size,
                              hipStream_t stream) {
  const float* features = (const float*)d_in[0];
  const float* pos      = (const float*)d_in[1];
  const float* W_embed  = (const float*)d_in[2];
  const float* Wq       = (const float*)d_in[3];
  const float* Wk       = (const float*)d_in[4];
  const float* Wv       = (const float*)d_in[5];
  const float* P1       = (const float*)d_in[6];
  const float* P2       = (const float*)d_in[7];
  const float* G1       = (const float*)d_in[8];
  const float* G2       = (const float*)d_in[9];
  const float* Wo       = (const float*)d_in[10];
  const float* Wc1      = (const float*)d_in[11];
  const float* Wc2      = (const float*)d_in[12];
  float* out = (float*)d_out;

  float* x    = (float*)d_ws;                  // NPTS*Dh
  float* kb   = x  + (size_t)NPTS*Dh;          // NPTS*Dh
  float* vb   = kb + (size_t)NPTS*Dh;          // NPTS*Dh
  int*   idxb = (int*)(vb + (size_t)NPTS*Dh);  // NPTS*KNN
  float* part = (float*)(idxb + (size_t)NPTS*KNN); // B*32*Dh

  embed_kernel<<<NPTS*Dh/256, 256, 0, stream>>>(features, W_embed, x);
  knn_kernel<<<dim3(NN/64, BB), 64, 0, stream>>>(pos, idxb);

  for (int l = 0; l < 2; l++) {
    kv_kernel<<<dim3(NPTS/32, 2), 128, 0, stream>>>(x, Wk + l*Dh*Dh, Wv + l*Dh*Dh, kb, vb);
    fused_layer_kernel<<<NPTS/NP, NP*128, 0, stream>>>(
        x, kb, vb, idxb, pos,
        Wq + l*Dh*Dh, P1 + l*3*Dh, P2 + l*Dh*Dh,
        G1 + l*Dh*Dh, G2 + l*Dh*Dh, Wo + l*Dh*Dh);
  }

  pool_part_kernel<<<dim3(32, BB), 128, 0, stream>>>(x, part);
  head_kernel<<<BB, 128, 0, stream>>>(part, Wc1, Wc2, out);
}

// Round 2
// 1993.549 us; speedup vs baseline: 3.4646x; 3.4646x over previous
//
#include <hip/hip_runtime.h>
#include <float.h>

// Problem constants
#define BB 8
#define NN 4096
#define KNN 16
#define Dh 128
#define NPTS (BB*NN)          // 32768

typedef __attribute__((ext_vector_type(8))) short bf16x8;   // 8 bf16 = 4 VGPRs
typedef __attribute__((ext_vector_type(4))) float f32x4;    // MFMA 16x16 accumulator

#define MFMA16(a,b,c) __builtin_amdgcn_mfma_f32_16x16x32_bf16(a,b,c,0,0,0)

__device__ __forceinline__ unsigned short f2b(float f) {   // f32 -> bf16 bits (RNE)
  union { float f; unsigned u; } v; v.f = f;
  unsigned r = v.u + 0x7fff + ((v.u >> 16) & 1);
  return (unsigned short)(r >> 16);
}
__device__ __forceinline__ float b2f(unsigned short s) {
  union { unsigned u; float f; } v; v.u = ((unsigned)s) << 16; return v.f;
}

// ---------------------------------------------------------------------------
// x = relu(features @ W_embed)   [B*N,3] @ [3,128], f32 out
__global__ __launch_bounds__(256) void embed_kernel(
    const float* __restrict__ f, const float* __restrict__ We, float* __restrict__ x) {
  int i = blockIdx.x * 256 + threadIdx.x;
  if (i >= NPTS * Dh) return;
  int p = i >> 7, d = i & 127;
  float f0 = f[p*3+0], f1 = f[p*3+1], f2 = f[p*3+2];
  float v = f0 * We[0*Dh + d] + f1 * We[1*Dh + d] + f2 * We[2*Dh + d];
  x[i] = fmaxf(v, 0.f);
}

// ---------------------------------------------------------------------------
// kNN (unchanged from passing round — tie-break matches reference top_k)
__global__ __launch_bounds__(64) void knn_kernel(
    const float* __restrict__ pos, int* __restrict__ idxout) {
  __shared__ float px[NN], py[NN], pz[NN], sq[NN];   // 64 KB
  int b = blockIdx.y;
  const float* pb = pos + (size_t)b * NN * 3;
  for (int i = threadIdx.x; i < NN; i += 64) {
    float X = pb[i*3+0], Y = pb[i*3+1], Z = pb[i*3+2];
    px[i] = X; py[i] = Y; pz[i] = Z;
    sq[i] = X*X + Y*Y + Z*Z;
  }
  __syncthreads();

  int n = blockIdx.x * 64 + threadIdx.x;
  float qx = px[n], qy = py[n], qz = pz[n], qs = sq[n];

  float val[KNN]; int ind[KNN];
  #pragma unroll
  for (int i = 0; i < KNN; i++) { val[i] = FLT_MAX; ind[i] = 0; }
  float cmax = FLT_MAX; int cslot = 0;

  for (int m = 0; m < NN; m++) {
    float dot = qx*px[m] + qy*py[m] + qz*pz[m];
    float d2 = qs + sq[m] - 2.f*dot;
    if (d2 < cmax) {
      #pragma unroll
      for (int i = 0; i < KNN; i++) if (i == cslot) { val[i] = d2; ind[i] = m; }
      cmax = val[0]; cslot = 0;
      #pragma unroll
      for (int i = 1; i < KNN; i++) if (val[i] >= cmax) { cmax = val[i]; cslot = i; }
    }
  }
  int base = (b*NN + n) * KNN;
  #pragma unroll
  for (int i = 0; i < KNN; i++) idxout[base + i] = b*NN + ind[i];
}

// ---------------------------------------------------------------------------
// Weight prep: WT[l][o][i] = bf16(W[l][i][o])  (transpose + convert, [2][128][128])
__global__ __launch_bounds__(256) void wprep_kernel(
    const float* __restrict__ W, unsigned short* __restrict__ WT) {
  int m = blockIdx.y;
  int t = blockIdx.x * 256 + threadIdx.x;   // 0..16383
  int o = t >> 7, i = t & 127;
  WT[m*16384 + o*128 + i] = f2b(W[m*16384 + i*128 + o]);
}

// ---------------------------------------------------------------------------
// q/k/v = x @ {Wq,Wk,Wv}: [32768,128]@[128,128] x3, bf16 out. 4 waves/block,
// each wave does 16 rows. A-frag: lane row=l&15, k=(l>>4)*8+j (bf16x8 from f32 x).
__global__ __launch_bounds__(256) void qkv_kernel(
    const float* __restrict__ x,
    const unsigned short* __restrict__ QT, const unsigned short* __restrict__ KT,
    const unsigned short* __restrict__ VT,
    unsigned short* __restrict__ qb, unsigned short* __restrict__ kb,
    unsigned short* __restrict__ vb) {
  int w = threadIdx.x >> 6, l = threadIdx.x & 63;
  int lr = l & 15, lg = l >> 4;
  int R = blockIdx.x * 64 + w * 16;
  const float* xr = x + (size_t)(R + lr) * Dh + lg * 8;
  bf16x8 a[4];
  #pragma unroll
  for (int kt = 0; kt < 4; kt++) {
    bf16x8 av;
    #pragma unroll
    for (int j = 0; j < 8; j++) av[j] = (short)f2b(xr[kt*32 + j]);
    a[kt] = av;
  }
  const unsigned short* Ws[3] = {QT, KT, VT};
  unsigned short* Os[3] = {qb, kb, vb};
  #pragma unroll
  for (int m = 0; m < 3; m++) {
    const unsigned short* W = Ws[m];
    unsigned short* O = Os[m];
    #pragma unroll
    for (int n = 0; n < 8; n++) {
      f32x4 c = {0.f, 0.f, 0.f, 0.f};
      #pragma unroll
      for (int kt = 0; kt < 4; kt++)
        c = MFMA16(a[kt], *(const bf16x8*)&W[(n*16 + lr)*Dh + kt*32 + lg*8], c);
      #pragma unroll
      for (int r = 0; r < 4; r++)
        O[(size_t)(R + lg*4 + r)*Dh + n*16 + lr] = f2b(c[r]);
    }
  }
}

// ---------------------------------------------------------------------------
// Fused vector-attention block, one wave per point, MFMA 16x16x32 bf16.
// C/D layout: col = lane&15 (channel), row = (lane>>4)*4 + reg (neighbor).
// A-frag:     row = lane&15,            k  = (lane>>4)*8 + j.
// LDS trans tile [16][128] bf16 per point, XOR-swizzled (idx ^ ((row&7)<<3)),
// wave-private => no __syncthreads needed.
__global__ __launch_bounds__(256) void fused_mfma_kernel(
    float* __restrict__ x,
    const unsigned short* __restrict__ qb, const unsigned short* __restrict__ kb,
    const unsigned short* __restrict__ vb,
    const int* __restrict__ idxb, const float* __restrict__ pos,
    const float* __restrict__ P1,
    const unsigned short* __restrict__ P2T, const unsigned short* __restrict__ G1T,
    const unsigned short* __restrict__ G2T, const unsigned short* __restrict__ WoT) {
  __shared__ __align__(16) unsigned short trans[4][16*Dh];   // 16 KB
  __shared__ __align__(16) unsigned short aggv[4][Dh];       // 1 KB
  int pt = threadIdx.x >> 6, l = threadIdx.x & 63;
  int lr = l & 15, lg = l >> 4;
  int p = blockIdx.x * 4 + pt;
  unsigned short* tb = trans[pt];

  // neighbor ids: jA for A-frag rows (t1), jC for C-layout gathers
  int jA = idxb[p*KNN + lr];
  int jC[4];
  #pragma unroll
  for (int r = 0; r < 4; r++) jC[r] = idxb[p*KNN + lg*4 + r];

  float px0 = pos[p*3+0], py0 = pos[p*3+1], pz0 = pos[p*3+2];
  float rx = px0 - pos[jA*3+0], ry = py0 - pos[jA*3+1], rz = pz0 - pos[jA*3+2];

  // t1 = relu(rel @ P1) directly in A-frag layout (lane=neighbor lr)
  bf16x8 aT[4];
  #pragma unroll
  for (int kt = 0; kt < 4; kt++) {
    bf16x8 av;
    #pragma unroll
    for (int j = 0; j < 8; j++) {
      int c = kt*32 + lg*8 + j;
      av[j] = (short)f2b(fmaxf(rx*P1[c] + ry*P1[Dh+c] + rz*P1[2*Dh+c], 0.f));
    }
    aT[kt] = av;
  }

  // DELTA = t1 @ P2  (C-layout regs, f32)
  f32x4 dlt[8];
  #pragma unroll
  for (int n = 0; n < 8; n++) {
    f32x4 c = {0.f, 0.f, 0.f, 0.f};
    #pragma unroll
    for (int kt = 0; kt < 4; kt++)
      c = MFMA16(aT[kt], *(const bf16x8*)&P2T[(n*16 + lr)*Dh + kt*32 + lg*8], c);
    dlt[n] = c;
  }

  // g = q - kj + delta -> bf16 -> swizzled LDS tile (C-layout scatter)
  #pragma unroll
  for (int n = 0; n < 8; n++) {
    float q = b2f(qb[(size_t)p*Dh + n*16 + lr]);
    #pragma unroll
    for (int r = 0; r < 4; r++) {
      float kj = b2f(kb[(size_t)jC[r]*Dh + n*16 + lr]);
      int row = lg*4 + r, ch = n*16 + lr;
      tb[(row*Dh + ch) ^ ((row & 7) << 3)] = f2b(q - kj + dlt[n][r]);
    }
  }

  // read A-frags of g, H = relu(g @ G1)
  bf16x8 ag[4];
  #pragma unroll
  for (int kt = 0; kt < 4; kt++)
    ag[kt] = *(const bf16x8*)&tb[(lr*Dh + kt*32 + lg*8) ^ ((lr & 7) << 3)];
  f32x4 hh[8];
  #pragma unroll
  for (int n = 0; n < 8; n++) {
    f32x4 c = {0.f, 0.f, 0.f, 0.f};
    #pragma unroll
    for (int kt = 0; kt < 4; kt++)
      c = MFMA16(ag[kt], *(const bf16x8*)&G1T[(n*16 + lr)*Dh + kt*32 + lg*8], c);
    hh[n] = c;
  }
  #pragma unroll
  for (int n = 0; n < 8; n++) {
    #pragma unroll
    for (int r = 0; r < 4; r++) {
      int row = lg*4 + r, ch = n*16 + lr;
      tb[(row*Dh + ch) ^ ((row & 7) << 3)] = f2b(fmaxf(hh[n][r], 0.f));
    }
  }

  // LOGITS = H @ G2 (C-layout regs)
  bf16x8 ah[4];
  #pragma unroll
  for (int kt = 0; kt < 4; kt++)
    ah[kt] = *(const bf16x8*)&tb[(lr*Dh + kt*32 + lg*8) ^ ((lr & 7) << 3)];
  f32x4 lgt[8];
  #pragma unroll
  for (int n = 0; n < 8; n++) {
    f32x4 c = {0.f, 0.f, 0.f, 0.f};
    #pragma unroll
    for (int kt = 0; kt < 4; kt++)
      c = MFMA16(ah[kt], *(const bf16x8*)&G2T[(n*16 + lr)*Dh + kt*32 + lg*8], c);
    lgt[n] = c;
  }

  // softmax over 16 neighbors (4 regs local + shfl_xor 16/32), then
  // agg[ch] = sum_k attn*(vj+delta)
  float agg[8];
  #pragma unroll
  for (int n = 0; n < 8; n++) {
    f32x4 L = lgt[n];
    float m = fmaxf(fmaxf(L[0], L[1]), fmaxf(L[2], L[3]));
    m = fmaxf(m, __shfl_xor(m, 16));
    m = fmaxf(m, __shfl_xor(m, 32));
    float e0 = __expf(L[0]-m), e1 = __expf(L[1]-m);
    float e2 = __expf(L[2]-m), e3 = __expf(L[3]-m);
    float s = e0 + e1 + e2 + e3;
    s += __shfl_xor(s, 16);
    s += __shfl_xor(s, 32);
    float inv = 1.f / s;           // wave-uniform across the 4 groups
    float ws;
    ws  = e0 * (b2f(vb[(size_t)jC[0]*Dh + n*16 + lr]) + dlt[n][0]);
    ws += e1 * (b2f(vb[(size_t)jC[1]*Dh + n*16 + lr]) + dlt[n][1]);
    ws += e2 * (b2f(vb[(size_t)jC[2]*Dh + n*16 + lr]) + dlt[n][2]);
    ws += e3 * (b2f(vb[(size_t)jC[3]*Dh + n*16 + lr]) + dlt[n][3]);
    ws *= inv;
    ws += __shfl_xor(ws, 16);
    ws += __shfl_xor(ws, 32);
    agg[n] = ws;                   // replicated across lane groups
  }

  // broadcast agg via LDS, OUT = x + agg @ Wo (broadcast-A trick: all rows = agg)
  if (lg == 0) {
    #pragma unroll
    for (int n = 0; n < 8; n++) aggv[pt][n*16 + lr] = f2b(agg[n]);
  }
  bf16x8 aw[4];
  #pragma unroll
  for (int kt = 0; kt < 4; kt++)
    aw[kt] = *(const bf16x8*)&aggv[pt][kt*32 + lg*8];
  #pragma unroll
  for (int n = 0; n < 8; n++) {
    f32x4 c = {0.f, 0.f, 0.f, 0.f};
    #pragma unroll
    for (int kt = 0; kt < 4; kt++)
      c = MFMA16(aw[kt], *(const bf16x8*)&WoT[(n*16 + lr)*Dh + kt*32 + lg*8], c);
    if (lg == 0) {
      int ch = n*16 + lr;
      x[(size_t)p*Dh + ch] += c[0];   // rows identical; reg0 = row lg*4
    }
  }
}

// ---------------------------------------------------------------------------
// Global max-pool + classifier head (f32, unchanged)
__global__ __launch_bounds__(128) void pool_part_kernel(
    const float* __restrict__ x, float* __restrict__ part) {
  int b = blockIdx.y, chunk = blockIdx.x, d = threadIdx.x;
  const float* xb = x + ((size_t)b*NN + chunk*128) * Dh;
  float m = -FLT_MAX;
  for (int n = 0; n < 128; n++) m = fmaxf(m, xb[(size_t)n*Dh + d]);
  part[(b*32 + chunk)*Dh + d] = m;
}

__global__ __launch_bounds__(128) void head_kernel(
    const float* __restrict__ part, const float* __restrict__ W1,
    const float* __restrict__ W2, float* __restrict__ out) {
  int b = blockIdx.x, d = threadIdx.x;
  __shared__ float pooled[Dh], h[Dh];
  float m = -FLT_MAX;
  for (int c = 0; c < 32; c++) m = fmaxf(m, part[(b*32 + c)*Dh + d]);
  pooled[d] = m;
  __syncthreads();
  float acc = 0.f;
  for (int c = 0; c < Dh; c++) acc += pooled[c] * W1[c*Dh + d];
  h[d] = fmaxf(acc, 0.f);
  __syncthreads();
  if (d < 40) {
    float o = 0.f;
    for (int c = 0; c < Dh; c++) o += h[c] * W2[c*40 + d];
    out[b*40 + d] = o;
  }
}

// ---------------------------------------------------------------------------
extern "C" void kernel_launch(void* const* d_in, const int* in_sizes, int n_in,
                              void* d_out, int out_size, void* d_ws, size_t ws_size,
                              hipStream_t stream) {
  const float* features = (const float*)d_in[0];
  const float* pos      = (const float*)d_in[1];
  const float* W_embed  = (const float*)d_in[2];
  const float* Wq       = (const float*)d_in[3];
  const float* Wk       = (const float*)d_in[4];
  const float* Wv       = (const float*)d_in[5];
  const float* P1       = (const float*)d_in[6];
  const float* P2       = (const float*)d_in[7];
  const float* G1       = (const float*)d_in[8];
  const float* G2       = (const float*)d_in[9];
  const float* Wo       = (const float*)d_in[10];
  const float* Wc1      = (const float*)d_in[11];
  const float* Wc2      = (const float*)d_in[12];
  float* out = (float*)d_out;

  // workspace layout (16B-aligned slices)
  float* x    = (float*)d_ws;                               // NPTS*Dh f32   (16 MB)
  float* part = x + (size_t)NPTS*Dh;                        // 8*32*128 f32
  unsigned short* qb = (unsigned short*)(part + 8*32*128);  // NPTS*Dh bf16
  unsigned short* kb = qb + (size_t)NPTS*Dh;
  unsigned short* vb = kb + (size_t)NPTS*Dh;
  unsigned short* wT = vb + (size_t)NPTS*Dh;                // 7*2*16384 bf16
  int* idxb = (int*)(wT + 7*2*16384);                       // NPTS*KNN int

  unsigned short* QT  = wT + 0*32768;   // [2][128][128] each, transposed bf16
  unsigned short* KT  = wT + 1*32768;
  unsigned short* VT  = wT + 2*32768;
  unsigned short* P2T = wT + 3*32768;
  unsigned short* G1T = wT + 4*32768;
  unsigned short* G2T = wT + 5*32768;
  unsigned short* WoT = wT + 6*32768;

  wprep_kernel<<<dim3(64,2), 256, 0, stream>>>(Wq, QT);
  wprep_kernel<<<dim3(64,2), 256, 0, stream>>>(Wk, KT);
  wprep_kernel<<<dim3(64,2), 256, 0, stream>>>(Wv, VT);
  wprep_kernel<<<dim3(64,2), 256, 0, stream>>>(P2, P2T);
  wprep_kernel<<<dim3(64,2), 256, 0, stream>>>(G1, G1T);
  wprep_kernel<<<dim3(64,2), 256, 0, stream>>>(G2, G2T);
  wprep_kernel<<<dim3(64,2), 256, 0, stream>>>(Wo, WoT);

  embed_kernel<<<NPTS*Dh/256, 256, 0, stream>>>(features, W_embed, x);
  knn_kernel<<<dim3(NN/64, BB), 64, 0, stream>>>(pos, idxb);

  for (int l = 0; l < 2; l++) {
    qkv_kernel<<<NPTS/64, 256, 0, stream>>>(
        x, QT + l*16384, KT + l*16384, VT + l*16384, qb, kb, vb);
    fused_mfma_kernel<<<NPTS/4, 256, 0, stream>>>(
        x, qb, kb, vb, idxb, pos,
        P1 + l*3*Dh, P2T + l*16384, G1T + l*16384, G2T + l*16384, WoT + l*16384);
  }

  pool_part_kernel<<<dim3(32, BB), 128, 0, stream>>>(x, part);
  head_kernel<<<BB, 128, 0, stream>>>(part, Wc1, Wc2, out);
}

// Round 3
// 1614.619 us; speedup vs baseline: 4.2777x; 1.2347x over previous
//
#include <hip/hip_runtime.h>
#include <float.h>

// Problem constants
#define BB 8
#define NN 4096
#define KNN 16
#define Dh 128
#define NPTS (BB*NN)          // 32768
#define NPART 8               // kNN candidate partitions
#define PARTSZ (NN/NPART)     // 512

typedef __attribute__((ext_vector_type(8))) short bf16x8;   // 8 bf16 = 4 VGPRs
typedef __attribute__((ext_vector_type(4))) float f32x4;    // MFMA 16x16 accumulator

#define MFMA16(a,b,c) __builtin_amdgcn_mfma_f32_16x16x32_bf16(a,b,c,0,0,0)

__device__ __forceinline__ unsigned short f2b(float f) {   // f32 -> bf16 bits (RNE)
  union { float f; unsigned u; } v; v.f = f;
  unsigned r = v.u + 0x7fff + ((v.u >> 16) & 1);
  return (unsigned short)(r >> 16);
}
__device__ __forceinline__ float b2f(unsigned short s) {
  union { unsigned u; float f; } v; v.u = ((unsigned)s) << 16; return v.f;
}

// ---------------------------------------------------------------------------
// x = relu(features @ W_embed)   [B*N,3] @ [3,128], f32 out
__global__ __launch_bounds__(256) void embed_kernel(
    const float* __restrict__ f, const float* __restrict__ We, float* __restrict__ x) {
  int i = blockIdx.x * 256 + threadIdx.x;
  if (i >= NPTS * Dh) return;
  int p = i >> 7, d = i & 127;
  float f0 = f[p*3+0], f1 = f[p*3+1], f2 = f[p*3+2];
  float v = f0 * We[0*Dh + d] + f1 * We[1*Dh + d] + f2 * We[2*Dh + d];
  x[i] = fmaxf(v, 0.f);
}

// ---------------------------------------------------------------------------
// kNN stage 1: per-partition top-16. grid (NN/256, NPART, B), block 256.
// Thread = one query; scans its partition's 512 candidates staged in LDS.
// Identical d2 arithmetic + insert logic as the round-1/2 full scan.
__global__ __launch_bounds__(256) void knn_part_kernel(
    const float* __restrict__ pos, int* __restrict__ pidx) {
  __shared__ float4 cand[PARTSZ];     // 8 KB
  int b = blockIdx.z, part = blockIdx.y;
  const float* pb = pos + (size_t)b * NN * 3;
  int c0 = part * PARTSZ;
  for (int i = threadIdx.x; i < PARTSZ; i += 256) {
    float X = pb[(c0+i)*3+0], Y = pb[(c0+i)*3+1], Z = pb[(c0+i)*3+2];
    cand[i] = make_float4(X, Y, Z, X*X + Y*Y + Z*Z);
  }
  __syncthreads();

  int q = blockIdx.x * 256 + threadIdx.x;
  float qx = pb[q*3+0], qy = pb[q*3+1], qz = pb[q*3+2];
  float qs = qx*qx + qy*qy + qz*qz;

  float val[KNN]; int ind[KNN];
  #pragma unroll
  for (int i = 0; i < KNN; i++) { val[i] = FLT_MAX; ind[i] = 0; }
  float cmax = FLT_MAX; int cslot = 0;

  for (int m = 0; m < PARTSZ; m++) {
    float4 c = cand[m];
    float d2 = qs + c.w - 2.f*(qx*c.x + qy*c.y + qz*c.z);
    if (d2 < cmax) {                 // strict <: ties keep earlier index
      #pragma unroll
      for (int i = 0; i < KNN; i++) if (i == cslot) { val[i] = d2; ind[i] = m; }
      cmax = val[0]; cslot = 0;
      #pragma unroll
      for (int i = 1; i < KNN; i++) if (val[i] >= cmax) { cmax = val[i]; cslot = i; }
    }
  }
  int base = ((b*NN + q) * NPART + part) * KNN;
  #pragma unroll
  for (int i = 0; i < KNN; i++) pidx[base + i] = b*NN + c0 + ind[i];
}

// ---------------------------------------------------------------------------
// kNN stage 2: merge 8 partial top-16 lists (128 candidates) -> final top-16.
// d2 recomputed from pos (L2-resident); same formula/insert logic.
__global__ __launch_bounds__(256) void knn_merge_kernel(
    const float* __restrict__ pos, const int* __restrict__ pidx,
    int* __restrict__ idxout) {
  int p = blockIdx.x * 256 + threadIdx.x;       // global point id
  float qx = pos[p*3+0], qy = pos[p*3+1], qz = pos[p*3+2];
  float qs = qx*qx + qy*qy + qz*qz;

  float val[KNN]; int ind[KNN];
  #pragma unroll
  for (int i = 0; i < KNN; i++) { val[i] = FLT_MAX; ind[i] = 0; }
  float cmax = FLT_MAX; int cslot = 0;

  for (int t = 0; t < NPART*KNN; t++) {
    int j = pidx[(size_t)p*NPART*KNN + t];
    float X = pos[j*3+0], Y = pos[j*3+1], Z = pos[j*3+2];
    float sq = X*X + Y*Y + Z*Z;
    float d2 = qs + sq - 2.f*(qx*X + qy*Y + qz*Z);
    if (d2 < cmax) {
      #pragma unroll
      for (int i = 0; i < KNN; i++) if (i == cslot) { val[i] = d2; ind[i] = j; }
      cmax = val[0]; cslot = 0;
      #pragma unroll
      for (int i = 1; i < KNN; i++) if (val[i] >= cmax) { cmax = val[i]; cslot = i; }
    }
  }
  #pragma unroll
  for (int i = 0; i < KNN; i++) idxout[p*KNN + i] = ind[i];
}

// ---------------------------------------------------------------------------
// Weight prep (all 7 weights in one launch): WT[z][l][o][i] = bf16(W[z][l][i][o])
__global__ __launch_bounds__(256) void wprep_all_kernel(
    const float* __restrict__ W0, const float* __restrict__ W1,
    const float* __restrict__ W2, const float* __restrict__ W3,
    const float* __restrict__ W4, const float* __restrict__ W5,
    const float* __restrict__ W6, unsigned short* __restrict__ wT) {
  const float* srcs[7] = {W0, W1, W2, W3, W4, W5, W6};
  int z = blockIdx.z, m = blockIdx.y;
  const float* W = srcs[z] + m*16384;
  unsigned short* WT = wT + z*32768 + m*16384;
  int t = blockIdx.x * 256 + threadIdx.x;   // 0..16383
  int o = t >> 7, i = t & 127;
  WT[o*128 + i] = f2b(W[i*128 + o]);
}

// ---------------------------------------------------------------------------
// q/k/v = x @ {Wq,Wk,Wv}: [32768,128]@[128,128] x3, bf16 out. 4 waves/block,
// each wave does 16 rows. A-frag: lane row=l&15, k=(l>>4)*8+j (bf16x8 from f32 x).
__global__ __launch_bounds__(256) void qkv_kernel(
    const float* __restrict__ x,
    const unsigned short* __restrict__ QT, const unsigned short* __restrict__ KT,
    const unsigned short* __restrict__ VT,
    unsigned short* __restrict__ qb, unsigned short* __restrict__ kb,
    unsigned short* __restrict__ vb) {
  int w = threadIdx.x >> 6, l = threadIdx.x & 63;
  int lr = l & 15, lg = l >> 4;
  int R = blockIdx.x * 64 + w * 16;
  const float* xr = x + (size_t)(R + lr) * Dh + lg * 8;
  bf16x8 a[4];
  #pragma unroll
  for (int kt = 0; kt < 4; kt++) {
    bf16x8 av;
    #pragma unroll
    for (int j = 0; j < 8; j++) av[j] = (short)f2b(xr[kt*32 + j]);
    a[kt] = av;
  }
  const unsigned short* Ws[3] = {QT, KT, VT};
  unsigned short* Os[3] = {qb, kb, vb};
  #pragma unroll
  for (int m = 0; m < 3; m++) {
    const unsigned short* W = Ws[m];
    unsigned short* O = Os[m];
    #pragma unroll
    for (int n = 0; n < 8; n++) {
      f32x4 c = {0.f, 0.f, 0.f, 0.f};
      #pragma unroll
      for (int kt = 0; kt < 4; kt++)
        c = MFMA16(a[kt], *(const bf16x8*)&W[(n*16 + lr)*Dh + kt*32 + lg*8], c);
      #pragma unroll
      for (int r = 0; r < 4; r++)
        O[(size_t)(R + lg*4 + r)*Dh + n*16 + lr] = f2b(c[r]);
    }
  }
}

// ---------------------------------------------------------------------------
// Fused vector-attention block, one wave per point, MFMA 16x16x32 bf16.
// C/D layout: col = lane&15 (channel), row = (lane>>4)*4 + reg (neighbor).
// A-frag:     row = lane&15,            k  = (lane>>4)*8 + j.
// LDS trans tile [16][128] bf16 per point, XOR-swizzled, wave-private.
__global__ __launch_bounds__(256) void fused_mfma_kernel(
    float* __restrict__ x,
    const unsigned short* __restrict__ qb, const unsigned short* __restrict__ kb,
    const unsigned short* __restrict__ vb,
    const int* __restrict__ idxb, const float* __restrict__ pos,
    const float* __restrict__ P1,
    const unsigned short* __restrict__ P2T, const unsigned short* __restrict__ G1T,
    const unsigned short* __restrict__ G2T, const unsigned short* __restrict__ WoT) {
  __shared__ __align__(16) unsigned short trans[4][16*Dh];   // 16 KB
  __shared__ __align__(16) unsigned short aggv[4][Dh];       // 1 KB
  int pt = threadIdx.x >> 6, l = threadIdx.x & 63;
  int lr = l & 15, lg = l >> 4;
  int p = blockIdx.x * 4 + pt;
  unsigned short* tb = trans[pt];

  // neighbor ids: jA for A-frag rows (t1), jC for C-layout gathers
  int jA = idxb[p*KNN + lr];
  int jC[4];
  #pragma unroll
  for (int r = 0; r < 4; r++) jC[r] = idxb[p*KNN + lg*4 + r];

  float px0 = pos[p*3+0], py0 = pos[p*3+1], pz0 = pos[p*3+2];
  float rx = px0 - pos[jA*3+0], ry = py0 - pos[jA*3+1], rz = pz0 - pos[jA*3+2];

  // t1 = relu(rel @ P1) directly in A-frag layout (lane=neighbor lr)
  bf16x8 aT[4];
  #pragma unroll
  for (int kt = 0; kt < 4; kt++) {
    bf16x8 av;
    #pragma unroll
    for (int j = 0; j < 8; j++) {
      int c = kt*32 + lg*8 + j;
      av[j] = (short)f2b(fmaxf(rx*P1[c] + ry*P1[Dh+c] + rz*P1[2*Dh+c], 0.f));
    }
    aT[kt] = av;
  }

  // DELTA = t1 @ P2  (C-layout regs, f32)
  f32x4 dlt[8];
  #pragma unroll
  for (int n = 0; n < 8; n++) {
    f32x4 c = {0.f, 0.f, 0.f, 0.f};
    #pragma unroll
    for (int kt = 0; kt < 4; kt++)
      c = MFMA16(aT[kt], *(const bf16x8*)&P2T[(n*16 + lr)*Dh + kt*32 + lg*8], c);
    dlt[n] = c;
  }

  // g = q - kj + delta -> bf16 -> swizzled LDS tile (C-layout scatter)
  #pragma unroll
  for (int n = 0; n < 8; n++) {
    float q = b2f(qb[(size_t)p*Dh + n*16 + lr]);
    #pragma unroll
    for (int r = 0; r < 4; r++) {
      float kj = b2f(kb[(size_t)jC[r]*Dh + n*16 + lr]);
      int row = lg*4 + r, ch = n*16 + lr;
      tb[(row*Dh + ch) ^ ((row & 7) << 3)] = f2b(q - kj + dlt[n][r]);
    }
  }

  // read A-frags of g, H = relu(g @ G1)
  bf16x8 ag[4];
  #pragma unroll
  for (int kt = 0; kt < 4; kt++)
    ag[kt] = *(const bf16x8*)&tb[(lr*Dh + kt*32 + lg*8) ^ ((lr & 7) << 3)];
  f32x4 hh[8];
  #pragma unroll
  for (int n = 0; n < 8; n++) {
    f32x4 c = {0.f, 0.f, 0.f, 0.f};
    #pragma unroll
    for (int kt = 0; kt < 4; kt++)
      c = MFMA16(ag[kt], *(const bf16x8*)&G1T[(n*16 + lr)*Dh + kt*32 + lg*8], c);
    hh[n] = c;
  }
  #pragma unroll
  for (int n = 0; n < 8; n++) {
    #pragma unroll
    for (int r = 0; r < 4; r++) {
      int row = lg*4 + r, ch = n*16 + lr;
      tb[(row*Dh + ch) ^ ((row & 7) << 3)] = f2b(fmaxf(hh[n][r], 0.f));
    }
  }

  // LOGITS = H @ G2 (C-layout regs)
  bf16x8 ah[4];
  #pragma unroll
  for (int kt = 0; kt < 4; kt++)
    ah[kt] = *(const bf16x8*)&tb[(lr*Dh + kt*32 + lg*8) ^ ((lr & 7) << 3)];
  f32x4 lgt[8];
  #pragma unroll
  for (int n = 0; n < 8; n++) {
    f32x4 c = {0.f, 0.f, 0.f, 0.f};
    #pragma unroll
    for (int kt = 0; kt < 4; kt++)
      c = MFMA16(ah[kt], *(const bf16x8*)&G2T[(n*16 + lr)*Dh + kt*32 + lg*8], c);
    lgt[n] = c;
  }

  // softmax over 16 neighbors (4 regs local + shfl_xor 16/32), then
  // agg[ch] = sum_k attn*(vj+delta)
  float agg[8];
  #pragma unroll
  for (int n = 0; n < 8; n++) {
    f32x4 L = lgt[n];
    float m = fmaxf(fmaxf(L[0], L[1]), fmaxf(L[2], L[3]));
    m = fmaxf(m, __shfl_xor(m, 16));
    m = fmaxf(m, __shfl_xor(m, 32));
    float e0 = __expf(L[0]-m), e1 = __expf(L[1]-m);
    float e2 = __expf(L[2]-m), e3 = __expf(L[3]-m);
    float s = e0 + e1 + e2 + e3;
    s += __shfl_xor(s, 16);
    s += __shfl_xor(s, 32);
    float inv = 1.f / s;
    float ws;
    ws  = e0 * (b2f(vb[(size_t)jC[0]*Dh + n*16 + lr]) + dlt[n][0]);
    ws += e1 * (b2f(vb[(size_t)jC[1]*Dh + n*16 + lr]) + dlt[n][1]);
    ws += e2 * (b2f(vb[(size_t)jC[2]*Dh + n*16 + lr]) + dlt[n][2]);
    ws += e3 * (b2f(vb[(size_t)jC[3]*Dh + n*16 + lr]) + dlt[n][3]);
    ws *= inv;
    ws += __shfl_xor(ws, 16);
    ws += __shfl_xor(ws, 32);
    agg[n] = ws;
  }

  // broadcast agg via LDS, OUT = x + agg @ Wo (broadcast-A: all rows = agg)
  if (lg == 0) {
    #pragma unroll
    for (int n = 0; n < 8; n++) aggv[pt][n*16 + lr] = f2b(agg[n]);
  }
  bf16x8 aw[4];
  #pragma unroll
  for (int kt = 0; kt < 4; kt++)
    aw[kt] = *(const bf16x8*)&aggv[pt][kt*32 + lg*8];
  #pragma unroll
  for (int n = 0; n < 8; n++) {
    f32x4 c = {0.f, 0.f, 0.f, 0.f};
    #pragma unroll
    for (int kt = 0; kt < 4; kt++)
      c = MFMA16(aw[kt], *(const bf16x8*)&WoT[(n*16 + lr)*Dh + kt*32 + lg*8], c);
    if (lg == 0) {
      int ch = n*16 + lr;
      x[(size_t)p*Dh + ch] += c[0];
    }
  }
}

// ---------------------------------------------------------------------------
// Global max-pool + classifier head (f32)
__global__ __launch_bounds__(128) void pool_part_kernel(
    const float* __restrict__ x, float* __restrict__ part) {
  int b = blockIdx.y, chunk = blockIdx.x, d = threadIdx.x;
  const float* xb = x + ((size_t)b*NN + chunk*128) * Dh;
  float m = -FLT_MAX;
  for (int n = 0; n < 128; n++) m = fmaxf(m, xb[(size_t)n*Dh + d]);
  part[(b*32 + chunk)*Dh + d] = m;
}

__global__ __launch_bounds__(128) void head_kernel(
    const float* __restrict__ part, const float* __restrict__ W1,
    const float* __restrict__ W2, float* __restrict__ out) {
  int b = blockIdx.x, d = threadIdx.x;
  __shared__ float pooled[Dh], h[Dh];
  float m = -FLT_MAX;
  for (int c = 0; c < 32; c++) m = fmaxf(m, part[(b*32 + c)*Dh + d]);
  pooled[d] = m;
  __syncthreads();
  float acc = 0.f;
  for (int c = 0; c < Dh; c++) acc += pooled[c] * W1[c*Dh + d];
  h[d] = fmaxf(acc, 0.f);
  __syncthreads();
  if (d < 40) {
    float o = 0.f;
    for (int c = 0; c < Dh; c++) o += h[c] * W2[c*40 + d];
    out[b*40 + d] = o;
  }
}

// ---------------------------------------------------------------------------
extern "C" void kernel_launch(void* const* d_in, const int* in_sizes, int n_in,
                              void* d_out, int out_size, void* d_ws, size_t ws_size,
                              hipStream_t stream) {
  const float* features = (const float*)d_in[0];
  const float* pos      = (const float*)d_in[1];
  const float* W_embed  = (const float*)d_in[2];
  const float* Wq       = (const float*)d_in[3];
  const float* Wk       = (const float*)d_in[4];
  const float* Wv       = (const float*)d_in[5];
  const float* P1       = (const float*)d_in[6];
  const float* P2       = (const float*)d_in[7];
  const float* G1       = (const float*)d_in[8];
  const float* G2       = (const float*)d_in[9];
  const float* Wo       = (const float*)d_in[10];
  const float* Wc1      = (const float*)d_in[11];
  const float* Wc2      = (const float*)d_in[12];
  float* out = (float*)d_out;

  // workspace layout (16B-aligned slices)
  float* x    = (float*)d_ws;                               // NPTS*Dh f32   (16 MB)
  float* part = x + (size_t)NPTS*Dh;                        // 8*32*128 f32
  unsigned short* qb = (unsigned short*)(part + 8*32*128);  // NPTS*Dh bf16
  unsigned short* kb = qb + (size_t)NPTS*Dh;
  unsigned short* vb = kb + (size_t)NPTS*Dh;
  unsigned short* wT = vb + (size_t)NPTS*Dh;                // 7*2*16384 bf16
  int* idxb = (int*)(wT + 7*2*16384);                       // NPTS*KNN int

  // kNN partial indices: aliased onto qb/kb/vb (24 MB region, needs 16.8 MB);
  // dead before qkv_kernel first writes those buffers.
  int* pidx = (int*)qb;

  unsigned short* QT  = wT + 0*32768;   // [2][128][128] each, transposed bf16
  unsigned short* KT  = wT + 1*32768;
  unsigned short* VT  = wT + 2*32768;
  unsigned short* P2T = wT + 3*32768;
  unsigned short* G1T = wT + 4*32768;
  unsigned short* G2T = wT + 5*32768;
  unsigned short* WoT = wT + 6*32768;

  knn_part_kernel<<<dim3(NN/256, NPART, BB), 256, 0, stream>>>(pos, pidx);
  knn_merge_kernel<<<NPTS/256, 256, 0, stream>>>(pos, pidx, idxb);

  wprep_all_kernel<<<dim3(64, 2, 7), 256, 0, stream>>>(Wq, Wk, Wv, P2, G1, G2, Wo, wT);
  embed_kernel<<<NPTS*Dh/256, 256, 0, stream>>>(features, W_embed, x);

  for (int l = 0; l < 2; l++) {
    qkv_kernel<<<NPTS/64, 256, 0, stream>>>(
        x, QT + l*16384, KT + l*16384, VT + l*16384, qb, kb, vb);
    fused_mfma_kernel<<<NPTS/4, 256, 0, stream>>>(
        x, qb, kb, vb, idxb, pos,
        P1 + l*3*Dh, P2T + l*16384, G1T + l*16384, G2T + l*16384, WoT + l*16384);
  }

  pool_part_kernel<<<dim3(32, BB), 128, 0, stream>>>(x, part);
  head_kernel<<<BB, 128, 0, stream>>>(part, Wc1, Wc2, out);
}

// Round 4
// 1140.601 us; speedup vs baseline: 6.0555x; 1.4156x over previous
//
#include <hip/hip_runtime.h>
#include <float.h>

// Problem constants
#define BB 8
#define NN 4096
#define KNN 16
#define Dh 128
#define NPTS (BB*NN)          // 32768
#define NPART 8               // kNN candidate partitions
#define PARTSZ (NN/NPART)     // 512

typedef __attribute__((ext_vector_type(8))) short bf16x8;   // 8 bf16 = 4 VGPRs
typedef __attribute__((ext_vector_type(8))) unsigned short u16x8;
typedef __attribute__((ext_vector_type(4))) float f32x4;    // MFMA 16x16 accumulator

#define MFMA16(a,b,c) __builtin_amdgcn_mfma_f32_16x16x32_bf16(a,b,c,0,0,0)

__device__ __forceinline__ unsigned short f2b(float f) {   // f32 -> bf16 bits (RNE)
  union { float f; unsigned u; } v; v.f = f;
  unsigned r = v.u + 0x7fff + ((v.u >> 16) & 1);
  return (unsigned short)(r >> 16);
}
__device__ __forceinline__ float b2f(unsigned short s) {
  union { unsigned u; float f; } v; v.u = ((unsigned)s) << 16; return v.f;
}

// ---------------------------------------------------------------------------
// x = relu(features @ W_embed)   [B*N,3] @ [3,128], f32 out
__global__ __launch_bounds__(256) void embed_kernel(
    const float* __restrict__ f, const float* __restrict__ We, float* __restrict__ x) {
  int i = blockIdx.x * 256 + threadIdx.x;
  if (i >= NPTS * Dh) return;
  int p = i >> 7, d = i & 127;
  float f0 = f[p*3+0], f1 = f[p*3+1], f2 = f[p*3+2];
  float v = f0 * We[0*Dh + d] + f1 * We[1*Dh + d] + f2 * We[2*Dh + d];
  x[i] = fmaxf(v, 0.f);
}

// ---------------------------------------------------------------------------
// kNN stage 1: per-partition top-16. grid (NN/256, NPART, B), block 256.
__global__ __launch_bounds__(256) void knn_part_kernel(
    const float* __restrict__ pos, unsigned short* __restrict__ pidx) {
  __shared__ float4 cand[PARTSZ];     // 8 KB
  int b = blockIdx.z, part = blockIdx.y;
  const float* pb = pos + (size_t)b * NN * 3;
  int c0 = part * PARTSZ;
  for (int i = threadIdx.x; i < PARTSZ; i += 256) {
    float X = pb[(c0+i)*3+0], Y = pb[(c0+i)*3+1], Z = pb[(c0+i)*3+2];
    cand[i] = make_float4(X, Y, Z, X*X + Y*Y + Z*Z);
  }
  __syncthreads();

  int q = blockIdx.x * 256 + threadIdx.x;
  float qx = pb[q*3+0], qy = pb[q*3+1], qz = pb[q*3+2];
  float qs = qx*qx + qy*qy + qz*qz;

  float val[KNN]; int ind[KNN];
  #pragma unroll
  for (int i = 0; i < KNN; i++) { val[i] = FLT_MAX; ind[i] = 0; }
  float cmax = FLT_MAX; int cslot = 0;

  for (int m = 0; m < PARTSZ; m++) {
    float4 c = cand[m];
    float d2 = qs + c.w - 2.f*(qx*c.x + qy*c.y + qz*c.z);
    if (d2 < cmax) {                 // strict <: ties keep earlier index
      #pragma unroll
      for (int i = 0; i < KNN; i++) if (i == cslot) { val[i] = d2; ind[i] = m; }
      cmax = val[0]; cslot = 0;
      #pragma unroll
      for (int i = 1; i < KNN; i++) if (val[i] >= cmax) { cmax = val[i]; cslot = i; }
    }
  }
  size_t base = ((size_t)(b*NN + q) * NPART + part) * KNN;
  #pragma unroll
  for (int i = 0; i < KNN; i++) pidx[base + i] = (unsigned short)(b*NN + c0 + ind[i]);
}

// ---------------------------------------------------------------------------
// kNN stage 2: merge 8 partial top-16 lists (128 candidates) -> final top-16.
__global__ __launch_bounds__(256) void knn_merge_kernel(
    const float* __restrict__ pos, const unsigned short* __restrict__ pidx,
    unsigned short* __restrict__ idxout) {
  int p = blockIdx.x * 256 + threadIdx.x;       // global point id
  float qx = pos[p*3+0], qy = pos[p*3+1], qz = pos[p*3+2];
  float qs = qx*qx + qy*qy + qz*qz;

  float val[KNN]; int ind[KNN];
  #pragma unroll
  for (int i = 0; i < KNN; i++) { val[i] = FLT_MAX; ind[i] = 0; }
  float cmax = FLT_MAX; int cslot = 0;

  for (int t = 0; t < NPART*KNN; t++) {
    int j = pidx[(size_t)p*NPART*KNN + t];
    float X = pos[j*3+0], Y = pos[j*3+1], Z = pos[j*3+2];
    float sq = X*X + Y*Y + Z*Z;
    float d2 = qs + sq - 2.f*(qx*X + qy*Y + qz*Z);
    if (d2 < cmax) {
      #pragma unroll
      for (int i = 0; i < KNN; i++) if (i == cslot) { val[i] = d2; ind[i] = j; }
      cmax = val[0]; cslot = 0;
      #pragma unroll
      for (int i = 1; i < KNN; i++) if (val[i] >= cmax) { cmax = val[i]; cslot = i; }
    }
  }
  #pragma unroll
  for (int i = 0; i < KNN; i++) idxout[(size_t)p*KNN + i] = (unsigned short)ind[i];
}

// ---------------------------------------------------------------------------
// Weight prep (all 7 weights in one launch): WT[z][l][o][i] = bf16(W[z][l][i][o])
__global__ __launch_bounds__(256) void wprep_all_kernel(
    const float* __restrict__ W0, const float* __restrict__ W1,
    const float* __restrict__ W2, const float* __restrict__ W3,
    const float* __restrict__ W4, const float* __restrict__ W5,
    const float* __restrict__ W6, unsigned short* __restrict__ wT) {
  const float* srcs[7] = {W0, W1, W2, W3, W4, W5, W6};
  int z = blockIdx.z, m = blockIdx.y;
  const float* W = srcs[z] + m*16384;
  unsigned short* WT = wT + z*32768 + m*16384;
  int t = blockIdx.x * 256 + threadIdx.x;   // 0..16383
  int o = t >> 7, i = t & 127;
  WT[o*128 + i] = f2b(W[i*128 + o]);
}

// ---------------------------------------------------------------------------
// q/k/v = x @ {Wq,Wk,Wv}: [32768,128]@[128,128] x3, bf16 out. 4 waves/block,
// each wave does 16 rows. A-frag: lane row=l&15, k=(l>>4)*8+j.
__global__ __launch_bounds__(256) void qkv_kernel(
    const float* __restrict__ x,
    const unsigned short* __restrict__ QT, const unsigned short* __restrict__ KT,
    const unsigned short* __restrict__ VT,
    unsigned short* __restrict__ qb, unsigned short* __restrict__ kb,
    unsigned short* __restrict__ vb) {
  int w = threadIdx.x >> 6, l = threadIdx.x & 63;
  int lr = l & 15, lg = l >> 4;
  int R = blockIdx.x * 64 + w * 16;
  const float* xr = x + (size_t)(R + lr) * Dh + lg * 8;
  bf16x8 a[4];
  #pragma unroll
  for (int kt = 0; kt < 4; kt++) {
    bf16x8 av;
    #pragma unroll
    for (int j = 0; j < 8; j++) av[j] = (short)f2b(xr[kt*32 + j]);
    a[kt] = av;
  }
  const unsigned short* Ws[3] = {QT, KT, VT};
  unsigned short* Os[3] = {qb, kb, vb};
  #pragma unroll
  for (int m = 0; m < 3; m++) {
    const unsigned short* W = Ws[m];
    unsigned short* O = Os[m];
    #pragma unroll
    for (int n = 0; n < 8; n++) {
      f32x4 c = {0.f, 0.f, 0.f, 0.f};
      #pragma unroll
      for (int kt = 0; kt < 4; kt++)
        c = MFMA16(a[kt], *(const bf16x8*)&W[(n*16 + lr)*Dh + kt*32 + lg*8], c);
      #pragma unroll
      for (int r = 0; r < 4; r++)
        O[(size_t)(R + lg*4 + r)*Dh + n*16 + lr] = f2b(c[r]);
    }
  }
}

// ---------------------------------------------------------------------------
// Mega fused vector-attention block. 256 blocks (1/CU) x 512 thr (8 waves).
// Per block: stage P2T/G1T/G2T into LDS (XOR-swizzled) once; each wave then
// processes 16 points. Per point: one wave, MFMA 16x16x32 bf16.
// C/D layout: col = lane&15 (channel), row = (lane>>4)*4 + reg (neighbor).
// A-frag:     row = lane&15,            k  = (lane>>4)*8 + j.
// Writes agg (bf16); the Wo residual update runs in xupd_kernel.
__global__ __launch_bounds__(512, 2) void fused_mega_kernel(
    const unsigned short* __restrict__ qb, const unsigned short* __restrict__ kb,
    const unsigned short* __restrict__ vb,
    const unsigned short* __restrict__ idxb, const float* __restrict__ pos,
    const float* __restrict__ P1,
    const unsigned short* __restrict__ P2T, const unsigned short* __restrict__ G1T,
    const unsigned short* __restrict__ G2T, unsigned short* __restrict__ aggb) {
  __shared__ __align__(16) unsigned short wB[3][16384];    // 96 KB, swizzled
  __shared__ __align__(16) unsigned short trans[8][2048];  // 32 KB (4 KB/wave)
  int tid = threadIdx.x;
  int wv = tid >> 6, l = tid & 63;
  int lr = l & 15, lg = l >> 4;
  const int swz = (lr & 7) << 3;

  // stage weights: same XOR swizzle as reads: idx ^ ((row&7)<<3), row = idx>>7
  {
    const unsigned short* srcs[3] = {P2T, G1T, G2T};
    #pragma unroll
    for (int z = 0; z < 3; z++) {
      const unsigned short* src = srcs[z];
      for (int t = tid * 8; t < 16384; t += 512 * 8) {
        int dst = t ^ (((t >> 7) & 7) << 3);
        *(u16x8*)&wB[z][dst] = *(const u16x8*)&src[t];
      }
    }
  }
  __syncthreads();

  unsigned short* tb = trans[wv];
  int p0 = blockIdx.x * 128 + wv * 16;

  #pragma unroll 1
  for (int i = 0; i < 16; i++) {
    int p = p0 + i;

    // neighbor ids: jA for A-frag rows (t1), jC for C-layout gathers
    int jA = idxb[(size_t)p*KNN + lr];
    int jC[4];
    #pragma unroll
    for (int r = 0; r < 4; r++) jC[r] = idxb[(size_t)p*KNN + lg*4 + r];

    float px0 = pos[p*3+0], py0 = pos[p*3+1], pz0 = pos[p*3+2];
    float rx = px0 - pos[jA*3+0], ry = py0 - pos[jA*3+1], rz = pz0 - pos[jA*3+2];

    // t1 = relu(rel @ P1) directly in A-frag layout (lane=neighbor lr)
    bf16x8 aT[4];
    #pragma unroll
    for (int kt = 0; kt < 4; kt++) {
      bf16x8 av;
      #pragma unroll
      for (int j = 0; j < 8; j++) {
        int c = kt*32 + lg*8 + j;
        av[j] = (short)f2b(fmaxf(rx*P1[c] + ry*P1[Dh+c] + rz*P1[2*Dh+c], 0.f));
      }
      aT[kt] = av;
    }

    // DELTA = t1 @ P2  (C-layout regs, f32); B-frags from LDS
    f32x4 dlt[8];
    #pragma unroll
    for (int n = 0; n < 8; n++) {
      f32x4 c = {0.f, 0.f, 0.f, 0.f};
      #pragma unroll
      for (int kt = 0; kt < 4; kt++)
        c = MFMA16(aT[kt], *(const bf16x8*)&wB[0][((n*16 + lr)*Dh + kt*32 + lg*8) ^ swz], c);
      dlt[n] = c;
    }

    // g = q - kj + delta -> bf16 -> swizzled LDS tile (C-layout scatter)
    #pragma unroll
    for (int n = 0; n < 8; n++) {
      float q = b2f(qb[(size_t)p*Dh + n*16 + lr]);
      #pragma unroll
      for (int r = 0; r < 4; r++) {
        float kj = b2f(kb[(size_t)jC[r]*Dh + n*16 + lr]);
        int row = lg*4 + r, ch = n*16 + lr;
        tb[(row*Dh + ch) ^ ((row & 7) << 3)] = f2b(q - kj + dlt[n][r]);
      }
    }

    // read A-frags of g, H = relu(g @ G1)
    bf16x8 ag[4];
    #pragma unroll
    for (int kt = 0; kt < 4; kt++)
      ag[kt] = *(const bf16x8*)&tb[(lr*Dh + kt*32 + lg*8) ^ swz];
    f32x4 hh[8];
    #pragma unroll
    for (int n = 0; n < 8; n++) {
      f32x4 c = {0.f, 0.f, 0.f, 0.f};
      #pragma unroll
      for (int kt = 0; kt < 4; kt++)
        c = MFMA16(ag[kt], *(const bf16x8*)&wB[1][((n*16 + lr)*Dh + kt*32 + lg*8) ^ swz], c);
      hh[n] = c;
    }
    #pragma unroll
    for (int n = 0; n < 8; n++) {
      #pragma unroll
      for (int r = 0; r < 4; r++) {
        int row = lg*4 + r, ch = n*16 + lr;
        tb[(row*Dh + ch) ^ ((row & 7) << 3)] = f2b(fmaxf(hh[n][r], 0.f));
      }
    }

    // LOGITS = H @ G2 (C-layout regs)
    bf16x8 ah[4];
    #pragma unroll
    for (int kt = 0; kt < 4; kt++)
      ah[kt] = *(const bf16x8*)&tb[(lr*Dh + kt*32 + lg*8) ^ swz];
    f32x4 lgt[8];
    #pragma unroll
    for (int n = 0; n < 8; n++) {
      f32x4 c = {0.f, 0.f, 0.f, 0.f};
      #pragma unroll
      for (int kt = 0; kt < 4; kt++)
        c = MFMA16(ah[kt], *(const bf16x8*)&wB[2][((n*16 + lr)*Dh + kt*32 + lg*8) ^ swz], c);
      lgt[n] = c;
    }

    // softmax over 16 neighbors (4 regs local + shfl_xor 16/32), then
    // agg[ch] = sum_k attn*(vj+delta)
    #pragma unroll
    for (int n = 0; n < 8; n++) {
      f32x4 L = lgt[n];
      float m = fmaxf(fmaxf(L[0], L[1]), fmaxf(L[2], L[3]));
      m = fmaxf(m, __shfl_xor(m, 16));
      m = fmaxf(m, __shfl_xor(m, 32));
      float e0 = __expf(L[0]-m), e1 = __expf(L[1]-m);
      float e2 = __expf(L[2]-m), e3 = __expf(L[3]-m);
      float s = e0 + e1 + e2 + e3;
      s += __shfl_xor(s, 16);
      s += __shfl_xor(s, 32);
      float inv = 1.f / s;
      float ws;
      ws  = e0 * (b2f(vb[(size_t)jC[0]*Dh + n*16 + lr]) + dlt[n][0]);
      ws += e1 * (b2f(vb[(size_t)jC[1]*Dh + n*16 + lr]) + dlt[n][1]);
      ws += e2 * (b2f(vb[(size_t)jC[2]*Dh + n*16 + lr]) + dlt[n][2]);
      ws += e3 * (b2f(vb[(size_t)jC[3]*Dh + n*16 + lr]) + dlt[n][3]);
      ws *= inv;
      ws += __shfl_xor(ws, 16);
      ws += __shfl_xor(ws, 32);
      if (lg == 0) aggb[(size_t)p*Dh + n*16 + lr] = f2b(ws);
    }
  }
}

// ---------------------------------------------------------------------------
// x += aggb @ Wo : [32768,128]@[128,128], f32 accumulate into x.
__global__ __launch_bounds__(256) void xupd_kernel(
    float* __restrict__ x, const unsigned short* __restrict__ aggb,
    const unsigned short* __restrict__ WoT) {
  int w = threadIdx.x >> 6, l = threadIdx.x & 63;
  int lr = l & 15, lg = l >> 4;
  int R = blockIdx.x * 64 + w * 16;
  bf16x8 a[4];
  #pragma unroll
  for (int kt = 0; kt < 4; kt++)
    a[kt] = *(const bf16x8*)&aggb[(size_t)(R + lr)*Dh + kt*32 + lg*8];
  #pragma unroll
  for (int n = 0; n < 8; n++) {
    f32x4 c = {0.f, 0.f, 0.f, 0.f};
    #pragma unroll
    for (int kt = 0; kt < 4; kt++)
      c = MFMA16(a[kt], *(const bf16x8*)&WoT[(n*16 + lr)*Dh + kt*32 + lg*8], c);
    #pragma unroll
    for (int r = 0; r < 4; r++)
      x[(size_t)(R + lg*4 + r)*Dh + n*16 + lr] += c[r];
  }
}

// ---------------------------------------------------------------------------
// Global max-pool + classifier head (f32)
__global__ __launch_bounds__(128) void pool_part_kernel(
    const float* __restrict__ x, float* __restrict__ part) {
  int b = blockIdx.y, chunk = blockIdx.x, d = threadIdx.x;
  const float* xb = x + ((size_t)b*NN + chunk*128) * Dh;
  float m = -FLT_MAX;
  for (int n = 0; n < 128; n++) m = fmaxf(m, xb[(size_t)n*Dh + d]);
  part[(b*32 + chunk)*Dh + d] = m;
}

__global__ __launch_bounds__(128) void head_kernel(
    const float* __restrict__ part, const float* __restrict__ W1,
    const float* __restrict__ W2, float* __restrict__ out) {
  int b = blockIdx.x, d = threadIdx.x;
  __shared__ float pooled[Dh], h[Dh];
  float m = -FLT_MAX;
  for (int c = 0; c < 32; c++) m = fmaxf(m, part[(b*32 + c)*Dh + d]);
  pooled[d] = m;
  __syncthreads();
  float acc = 0.f;
  for (int c = 0; c < Dh; c++) acc += pooled[c] * W1[c*Dh + d];
  h[d] = fmaxf(acc, 0.f);
  __syncthreads();
  if (d < 40) {
    float o = 0.f;
    for (int c = 0; c < Dh; c++) o += h[c] * W2[c*40 + d];
    out[b*40 + d] = o;
  }
}

// ---------------------------------------------------------------------------
extern "C" void kernel_launch(void* const* d_in, const int* in_sizes, int n_in,
                              void* d_out, int out_size, void* d_ws, size_t ws_size,
                              hipStream_t stream) {
  const float* features = (const float*)d_in[0];
  const float* pos      = (const float*)d_in[1];
  const float* W_embed  = (const float*)d_in[2];
  const float* Wq       = (const float*)d_in[3];
  const float* Wk       = (const float*)d_in[4];
  const float* Wv       = (const float*)d_in[5];
  const float* P1       = (const float*)d_in[6];
  const float* P2       = (const float*)d_in[7];
  const float* G1       = (const float*)d_in[8];
  const float* G2       = (const float*)d_in[9];
  const float* Wo       = (const float*)d_in[10];
  const float* Wc1      = (const float*)d_in[11];
  const float* Wc2      = (const float*)d_in[12];
  float* out = (float*)d_out;

  // workspace layout (16B-aligned slices)
  float* x = (float*)d_ws;                                   // NPTS*Dh f32 (16 MB)
  unsigned short* qb = (unsigned short*)(x + (size_t)NPTS*Dh); // NPTS*Dh bf16 (8 MB)
  unsigned short* kb = qb + (size_t)NPTS*Dh;
  unsigned short* vb = kb + (size_t)NPTS*Dh;
  unsigned short* wT = vb + (size_t)NPTS*Dh;                 // 7*2*16384 bf16
  unsigned short* aggb = wT + 7*2*16384;                     // NPTS*Dh bf16 (8 MB)
  unsigned short* idxb = aggb + (size_t)NPTS*Dh;             // NPTS*KNN u16 (1 MB)

  // kNN partial indices (u16): aliased onto qb/kb (needs 8.4 MB); dead before qkv.
  unsigned short* pidx = qb;
  // pooled partials: aliased onto qb (dead after last fused layer).
  float* part = (float*)qb;

  unsigned short* QT  = wT + 0*32768;   // [2][128][128] each, transposed bf16
  unsigned short* KT  = wT + 1*32768;
  unsigned short* VT  = wT + 2*32768;
  unsigned short* P2T = wT + 3*32768;
  unsigned short* G1T = wT + 4*32768;
  unsigned short* G2T = wT + 5*32768;
  unsigned short* WoT = wT + 6*32768;

  knn_part_kernel<<<dim3(NN/256, NPART, BB), 256, 0, stream>>>(pos, pidx);
  knn_merge_kernel<<<NPTS/256, 256, 0, stream>>>(pos, pidx, idxb);

  wprep_all_kernel<<<dim3(64, 2, 7), 256, 0, stream>>>(Wq, Wk, Wv, P2, G1, G2, Wo, wT);
  embed_kernel<<<NPTS*Dh/256, 256, 0, stream>>>(features, W_embed, x);

  for (int l = 0; l < 2; l++) {
    qkv_kernel<<<NPTS/64, 256, 0, stream>>>(
        x, QT + l*16384, KT + l*16384, VT + l*16384, qb, kb, vb);
    fused_mega_kernel<<<256, 512, 0, stream>>>(
        qb, kb, vb, idxb, pos,
        P1 + l*3*Dh, P2T + l*16384, G1T + l*16384, G2T + l*16384, aggb);
    xupd_kernel<<<NPTS/64, 256, 0, stream>>>(x, aggb, WoT + l*16384);
  }

  pool_part_kernel<<<dim3(32, BB), 128, 0, stream>>>(x, part);
  head_kernel<<<BB, 128, 0, stream>>>(part, Wc1, Wc2, out);
}

// Round 5
// 995.105 us; speedup vs baseline: 6.9408x; 1.1462x over previous
//
#include <hip/hip_runtime.h>
#include <float.h>

// Problem constants
#define BB 8
#define NN 4096
#define KNN 16
#define Dh 128
#define NPTS (BB*NN)          // 32768
#define NPART 8               // kNN candidate partitions
#define PARTSZ (NN/NPART)     // 512

typedef __attribute__((ext_vector_type(8))) short bf16x8;   // 8 bf16 = 4 VGPRs
typedef __attribute__((ext_vector_type(8))) unsigned short u16x8;
typedef __attribute__((ext_vector_type(4))) float f32x4;    // MFMA 16x16 accumulator

#define MFMA16(a,b,c) __builtin_amdgcn_mfma_f32_16x16x32_bf16(a,b,c,0,0,0)

__device__ __forceinline__ unsigned short f2b(float f) {   // f32 -> bf16 bits (RNE)
  union { float f; unsigned u; } v; v.f = f;
  unsigned r = v.u + 0x7fff + ((v.u >> 16) & 1);
  return (unsigned short)(r >> 16);
}
__device__ __forceinline__ float b2f(unsigned short s) {
  union { unsigned u; float f; } v; v.u = ((unsigned)s) << 16; return v.f;
}

// ---------------------------------------------------------------------------
// x = relu(features @ W_embed)   [B*N,3] @ [3,128], f32 out
__global__ __launch_bounds__(256) void embed_kernel(
    const float* __restrict__ f, const float* __restrict__ We, float* __restrict__ x) {
  int i = blockIdx.x * 256 + threadIdx.x;
  if (i >= NPTS * Dh) return;
  int p = i >> 7, d = i & 127;
  float f0 = f[p*3+0], f1 = f[p*3+1], f2 = f[p*3+2];
  float v = f0 * We[0*Dh + d] + f1 * We[1*Dh + d] + f2 * We[2*Dh + d];
  x[i] = fmaxf(v, 0.f);
}

// ---------------------------------------------------------------------------
// kNN stage 1: per-partition top-16 with buffered-drain insert batching.
// grid (NN/256, NPART, B), block 256. Thread = one query.
// Semantics provably identical to the serial insert scan: pushes pass a
// stale (>=) cmax, are re-checked against exact cmax at drain, applied in
// candidate order.
__global__ __launch_bounds__(256) void knn_part_kernel(
    const float* __restrict__ pos, unsigned short* __restrict__ pidx) {
  __shared__ float4 cand[PARTSZ];     // 8 KB
  int b = blockIdx.z, part = blockIdx.y;
  const float* pb = pos + (size_t)b * NN * 3;
  int c0 = part * PARTSZ;
  for (int i = threadIdx.x; i < PARTSZ; i += 256) {
    float X = pb[(c0+i)*3+0], Y = pb[(c0+i)*3+1], Z = pb[(c0+i)*3+2];
    cand[i] = make_float4(X, Y, Z, X*X + Y*Y + Z*Z);
  }
  __syncthreads();

  int q = blockIdx.x * 256 + threadIdx.x;
  float qx = pb[q*3+0], qy = pb[q*3+1], qz = pb[q*3+2];
  float qs = qx*qx + qy*qy + qz*qz;

  float val[KNN]; int ind[KNN];
  float cmax; int cslot;

  // fill phase: first 16 candidates take slots directly (no maintenance)
  #pragma unroll
  for (int t = 0; t < KNN; t++) {
    float4 c = cand[t];
    val[t] = qs + c.w - 2.f*(qx*c.x + qy*c.y + qz*c.z);
    ind[t] = t;
  }
  cmax = val[0]; cslot = 0;
  #pragma unroll
  for (int i = 1; i < KNN; i++)
    if (val[i] >= cmax) { cmax = val[i]; cslot = i; }   // evict latest among ties

  // pending FIFO (4 deep, static-indexed)
  float bv0 = 0.f, bv1 = 0.f, bv2 = 0.f, bv3 = 0.f;
  int   bi0 = 0,   bi1 = 0,   bi2 = 0,   bi3 = 0;
  int   cnt = 0;

#define DRAIN_SLOT(S, BV, BI)                                      \
  { bool act = ((S) < cnt) && ((BV) < cmax);                       \
    if (__ballot(act)) {                                           \
      _Pragma("unroll")                                            \
      for (int i = 0; i < KNN; i++) {                              \
        bool r = act && (i == cslot);                              \
        val[i] = r ? (BV) : val[i];                                \
        ind[i] = r ? (BI) : ind[i];                                \
      }                                                            \
      cmax = val[0]; cslot = 0;                                    \
      _Pragma("unroll")                                            \
      for (int i = 1; i < KNN; i++)                                \
        if (val[i] >= cmax) { cmax = val[i]; cslot = i; }          \
    } }
#define DRAIN_ALL                                                  \
  { DRAIN_SLOT(0, bv0, bi0) DRAIN_SLOT(1, bv1, bi1)                \
    DRAIN_SLOT(2, bv2, bi2) DRAIN_SLOT(3, bv3, bi3) cnt = 0; }

  for (int m = KNN; m < PARTSZ; m++) {
    float4 c = cand[m];
    float d2 = qs + c.w - 2.f*(qx*c.x + qy*c.y + qz*c.z);
    if (d2 < cmax) {                 // push (stale cmax: conservative superset)
      bv0 = (cnt == 0) ? d2 : bv0;  bi0 = (cnt == 0) ? m : bi0;
      bv1 = (cnt == 1) ? d2 : bv1;  bi1 = (cnt == 1) ? m : bi1;
      bv2 = (cnt == 2) ? d2 : bv2;  bi2 = (cnt == 2) ? m : bi2;
      bv3 = (cnt == 3) ? d2 : bv3;  bi3 = (cnt == 3) ? m : bi3;
      cnt++;
    }
    if (__ballot(cnt == 4)) DRAIN_ALL
  }
  if (__ballot(cnt > 0)) DRAIN_ALL   // final drain

#undef DRAIN_SLOT
#undef DRAIN_ALL

  size_t base = ((size_t)(b*NN + q) * NPART + part) * KNN;
  #pragma unroll
  for (int i = 0; i < KNN; i++) pidx[base + i] = (unsigned short)(b*NN + c0 + ind[i]);
}

// ---------------------------------------------------------------------------
// kNN stage 2: merge 8 partial top-16 lists (128 candidates) -> final top-16.
__global__ __launch_bounds__(256) void knn_merge_kernel(
    const float* __restrict__ pos, const unsigned short* __restrict__ pidx,
    unsigned short* __restrict__ idxout) {
  int p = blockIdx.x * 256 + threadIdx.x;       // global point id
  float qx = pos[p*3+0], qy = pos[p*3+1], qz = pos[p*3+2];
  float qs = qx*qx + qy*qy + qz*qz;

  float val[KNN]; int ind[KNN];
  #pragma unroll
  for (int i = 0; i < KNN; i++) { val[i] = FLT_MAX; ind[i] = 0; }
  float cmax = FLT_MAX; int cslot = 0;

  for (int t = 0; t < NPART*KNN; t++) {
    int j = pidx[(size_t)p*NPART*KNN + t];
    float X = pos[j*3+0], Y = pos[j*3+1], Z = pos[j*3+2];
    float sq = X*X + Y*Y + Z*Z;
    float d2 = qs + sq - 2.f*(qx*X + qy*Y + qz*Z);
    if (d2 < cmax) {
      #pragma unroll
      for (int i = 0; i < KNN; i++) if (i == cslot) { val[i] = d2; ind[i] = j; }
      cmax = val[0]; cslot = 0;
      #pragma unroll
      for (int i = 1; i < KNN; i++) if (val[i] >= cmax) { cmax = val[i]; cslot = i; }
    }
  }
  #pragma unroll
  for (int i = 0; i < KNN; i++) idxout[(size_t)p*KNN + i] = (unsigned short)ind[i];
}

// ---------------------------------------------------------------------------
// Weight prep (all 7 weights in one launch): WT[z][l][o][i] = bf16(W[z][l][i][o])
__global__ __launch_bounds__(256) void wprep_all_kernel(
    const float* __restrict__ W0, const float* __restrict__ W1,
    const float* __restrict__ W2, const float* __restrict__ W3,
    const float* __restrict__ W4, const float* __restrict__ W5,
    const float* __restrict__ W6, unsigned short* __restrict__ wT) {
  const float* srcs[7] = {W0, W1, W2, W3, W4, W5, W6};
  int z = blockIdx.z, m = blockIdx.y;
  const float* W = srcs[z] + m*16384;
  unsigned short* WT = wT + z*32768 + m*16384;
  int t = blockIdx.x * 256 + threadIdx.x;   // 0..16383
  int o = t >> 7, i = t & 127;
  WT[o*128 + i] = f2b(W[i*128 + o]);
}

// ---------------------------------------------------------------------------
// q/k/v = x @ {Wq,Wk,Wv}: [32768,128]@[128,128] x3, bf16 out. 4 waves/block,
// each wave does 16 rows. A-frag: lane row=l&15, k=(l>>4)*8+j.
__global__ __launch_bounds__(256) void qkv_kernel(
    const float* __restrict__ x,
    const unsigned short* __restrict__ QT, const unsigned short* __restrict__ KT,
    const unsigned short* __restrict__ VT,
    unsigned short* __restrict__ qb, unsigned short* __restrict__ kb,
    unsigned short* __restrict__ vb) {
  int w = threadIdx.x >> 6, l = threadIdx.x & 63;
  int lr = l & 15, lg = l >> 4;
  int R = blockIdx.x * 64 + w * 16;
  const float* xr = x + (size_t)(R + lr) * Dh + lg * 8;
  bf16x8 a[4];
  #pragma unroll
  for (int kt = 0; kt < 4; kt++) {
    bf16x8 av;
    #pragma unroll
    for (int j = 0; j < 8; j++) av[j] = (short)f2b(xr[kt*32 + j]);
    a[kt] = av;
  }
  const unsigned short* Ws[3] = {QT, KT, VT};
  unsigned short* Os[3] = {qb, kb, vb};
  #pragma unroll
  for (int m = 0; m < 3; m++) {
    const unsigned short* W = Ws[m];
    unsigned short* O = Os[m];
    #pragma unroll
    for (int n = 0; n < 8; n++) {
      f32x4 c = {0.f, 0.f, 0.f, 0.f};
      #pragma unroll
      for (int kt = 0; kt < 4; kt++)
        c = MFMA16(a[kt], *(const bf16x8*)&W[(n*16 + lr)*Dh + kt*32 + lg*8], c);
      #pragma unroll
      for (int r = 0; r < 4; r++)
        O[(size_t)(R + lg*4 + r)*Dh + n*16 + lr] = f2b(c[r]);
    }
  }
}

// ---------------------------------------------------------------------------
// Mega fused vector-attention block. 256 blocks (1/CU) x 512 thr (8 waves).
// Per block: stage P2T/G1T/G2T into LDS (XOR-swizzled) once; each wave then
// processes 16 points. Per point: one wave, MFMA 16x16x32 bf16.
// C/D layout: col = lane&15 (channel), row = (lane>>4)*4 + reg (neighbor).
// A-frag:     row = lane&15,            k  = (lane>>4)*8 + j.
// Writes agg (bf16); the Wo residual update runs in xupd_kernel.
__global__ __launch_bounds__(512, 2) void fused_mega_kernel(
    const unsigned short* __restrict__ qb, const unsigned short* __restrict__ kb,
    const unsigned short* __restrict__ vb,
    const unsigned short* __restrict__ idxb, const float* __restrict__ pos,
    const float* __restrict__ P1,
    const unsigned short* __restrict__ P2T, const unsigned short* __restrict__ G1T,
    const unsigned short* __restrict__ G2T, unsigned short* __restrict__ aggb) {
  __shared__ __align__(16) unsigned short wB[3][16384];    // 96 KB, swizzled
  __shared__ __align__(16) unsigned short trans[8][2048];  // 32 KB (4 KB/wave)
  int tid = threadIdx.x;
  int wv = tid >> 6, l = tid & 63;
  int lr = l & 15, lg = l >> 4;
  const int swz = (lr & 7) << 3;

  // stage weights: same XOR swizzle as reads: idx ^ ((row&7)<<3), row = idx>>7
  {
    const unsigned short* srcs[3] = {P2T, G1T, G2T};
    #pragma unroll
    for (int z = 0; z < 3; z++) {
      const unsigned short* src = srcs[z];
      for (int t = tid * 8; t < 16384; t += 512 * 8) {
        int dst = t ^ (((t >> 7) & 7) << 3);
        *(u16x8*)&wB[z][dst] = *(const u16x8*)&src[t];
      }
    }
  }
  __syncthreads();

  unsigned short* tb = trans[wv];
  int p0 = blockIdx.x * 128 + wv * 16;

  #pragma unroll 1
  for (int i = 0; i < 16; i++) {
    int p = p0 + i;

    // neighbor ids: jA for A-frag rows (t1), jC for C-layout gathers
    int jA = idxb[(size_t)p*KNN + lr];
    int jC[4];
    #pragma unroll
    for (int r = 0; r < 4; r++) jC[r] = idxb[(size_t)p*KNN + lg*4 + r];

    float px0 = pos[p*3+0], py0 = pos[p*3+1], pz0 = pos[p*3+2];
    float rx = px0 - pos[jA*3+0], ry = py0 - pos[jA*3+1], rz = pz0 - pos[jA*3+2];

    // t1 = relu(rel @ P1) directly in A-frag layout (lane=neighbor lr)
    bf16x8 aT[4];
    #pragma unroll
    for (int kt = 0; kt < 4; kt++) {
      bf16x8 av;
      #pragma unroll
      for (int j = 0; j < 8; j++) {
        int c = kt*32 + lg*8 + j;
        av[j] = (short)f2b(fmaxf(rx*P1[c] + ry*P1[Dh+c] + rz*P1[2*Dh+c], 0.f));
      }
      aT[kt] = av;
    }

    // DELTA = t1 @ P2  (C-layout regs, f32); B-frags from LDS
    f32x4 dlt[8];
    #pragma unroll
    for (int n = 0; n < 8; n++) {
      f32x4 c = {0.f, 0.f, 0.f, 0.f};
      #pragma unroll
      for (int kt = 0; kt < 4; kt++)
        c = MFMA16(aT[kt], *(const bf16x8*)&wB[0][((n*16 + lr)*Dh + kt*32 + lg*8) ^ swz], c);
      dlt[n] = c;
    }

    // g = q - kj + delta -> bf16 -> swizzled LDS tile (C-layout scatter)
    #pragma unroll
    for (int n = 0; n < 8; n++) {
      float q = b2f(qb[(size_t)p*Dh + n*16 + lr]);
      #pragma unroll
      for (int r = 0; r < 4; r++) {
        float kj = b2f(kb[(size_t)jC[r]*Dh + n*16 + lr]);
        int row = lg*4 + r, ch = n*16 + lr;
        tb[(row*Dh + ch) ^ ((row & 7) << 3)] = f2b(q - kj + dlt[n][r]);
      }
    }

    // read A-frags of g, H = relu(g @ G1)
    bf16x8 ag[4];
    #pragma unroll
    for (int kt = 0; kt < 4; kt++)
      ag[kt] = *(const bf16x8*)&tb[(lr*Dh + kt*32 + lg*8) ^ swz];
    f32x4 hh[8];
    #pragma unroll
    for (int n = 0; n < 8; n++) {
      f32x4 c = {0.f, 0.f, 0.f, 0.f};
      #pragma unroll
      for (int kt = 0; kt < 4; kt++)
        c = MFMA16(ag[kt], *(const bf16x8*)&wB[1][((n*16 + lr)*Dh + kt*32 + lg*8) ^ swz], c);
      hh[n] = c;
    }
    #pragma unroll
    for (int n = 0; n < 8; n++) {
      #pragma unroll
      for (int r = 0; r < 4; r++) {
        int row = lg*4 + r, ch = n*16 + lr;
        tb[(row*Dh + ch) ^ ((row & 7) << 3)] = f2b(fmaxf(hh[n][r], 0.f));
      }
    }

    // LOGITS = H @ G2 (C-layout regs)
    bf16x8 ah[4];
    #pragma unroll
    for (int kt = 0; kt < 4; kt++)
      ah[kt] = *(const bf16x8*)&tb[(lr*Dh + kt*32 + lg*8) ^ swz];
    f32x4 lgt[8];
    #pragma unroll
    for (int n = 0; n < 8; n++) {
      f32x4 c = {0.f, 0.f, 0.f, 0.f};
      #pragma unroll
      for (int kt = 0; kt < 4; kt++)
        c = MFMA16(ah[kt], *(const bf16x8*)&wB[2][((n*16 + lr)*Dh + kt*32 + lg*8) ^ swz], c);
      lgt[n] = c;
    }

    // softmax over 16 neighbors (4 regs local + shfl_xor 16/32), then
    // agg[ch] = sum_k attn*(vj+delta)
    #pragma unroll
    for (int n = 0; n < 8; n++) {
      f32x4 L = lgt[n];
      float m = fmaxf(fmaxf(L[0], L[1]), fmaxf(L[2], L[3]));
      m = fmaxf(m, __shfl_xor(m, 16));
      m = fmaxf(m, __shfl_xor(m, 32));
      float e0 = __expf(L[0]-m), e1 = __expf(L[1]-m);
      float e2 = __expf(L[2]-m), e3 = __expf(L[3]-m);
      float s = e0 + e1 + e2 + e3;
      s += __shfl_xor(s, 16);
      s += __shfl_xor(s, 32);
      float inv = 1.f / s;
      float ws;
      ws  = e0 * (b2f(vb[(size_t)jC[0]*Dh + n*16 + lr]) + dlt[n][0]);
      ws += e1 * (b2f(vb[(size_t)jC[1]*Dh + n*16 + lr]) + dlt[n][1]);
      ws += e2 * (b2f(vb[(size_t)jC[2]*Dh + n*16 + lr]) + dlt[n][2]);
      ws += e3 * (b2f(vb[(size_t)jC[3]*Dh + n*16 + lr]) + dlt[n][3]);
      ws *= inv;
      ws += __shfl_xor(ws, 16);
      ws += __shfl_xor(ws, 32);
      if (lg == 0) aggb[(size_t)p*Dh + n*16 + lr] = f2b(ws);
    }
  }
}

// ---------------------------------------------------------------------------
// x += aggb @ Wo : [32768,128]@[128,128], f32 accumulate into x.
__global__ __launch_bounds__(256) void xupd_kernel(
    float* __restrict__ x, const unsigned short* __restrict__ aggb,
    const unsigned short* __restrict__ WoT) {
  int w = threadIdx.x >> 6, l = threadIdx.x & 63;
  int lr = l & 15, lg = l >> 4;
  int R = blockIdx.x * 64 + w * 16;
  bf16x8 a[4];
  #pragma unroll
  for (int kt = 0; kt < 4; kt++)
    a[kt] = *(const bf16x8*)&aggb[(size_t)(R + lr)*Dh + kt*32 + lg*8];
  #pragma unroll
  for (int n = 0; n < 8; n++) {
    f32x4 c = {0.f, 0.f, 0.f, 0.f};
    #pragma unroll
    for (int kt = 0; kt < 4; kt++)
      c = MFMA16(a[kt], *(const bf16x8*)&WoT[(n*16 + lr)*Dh + kt*32 + lg*8], c);
    #pragma unroll
    for (int r = 0; r < 4; r++)
      x[(size_t)(R + lg*4 + r)*Dh + n*16 + lr] += c[r];
  }
}

// ---------------------------------------------------------------------------
// Global max-pool + classifier head (f32)
__global__ __launch_bounds__(128) void pool_part_kernel(
    const float* __restrict__ x, float* __restrict__ part) {
  int b = blockIdx.y, chunk = blockIdx.x, d = threadIdx.x;
  const float* xb = x + ((size_t)b*NN + chunk*128) * Dh;
  float m = -FLT_MAX;
  for (int n = 0; n < 128; n++) m = fmaxf(m, xb[(size_t)n*Dh + d]);
  part[(b*32 + chunk)*Dh + d] = m;
}

__global__ __launch_bounds__(128) void head_kernel(
    const float* __restrict__ part, const float* __restrict__ W1,
    const float* __restrict__ W2, float* __restrict__ out) {
  int b = blockIdx.x, d = threadIdx.x;
  __shared__ float pooled[Dh], h[Dh];
  float m = -FLT_MAX;
  for (int c = 0; c < 32; c++) m = fmaxf(m, part[(b*32 + c)*Dh + d]);
  pooled[d] = m;
  __syncthreads();
  float acc = 0.f;
  for (int c = 0; c < Dh; c++) acc += pooled[c] * W1[c*Dh + d];
  h[d] = fmaxf(acc, 0.f);
  __syncthreads();
  if (d < 40) {
    float o = 0.f;
    for (int c = 0; c < Dh; c++) o += h[c] * W2[c*40 + d];
    out[b*40 + d] = o;
  }
}

// ---------------------------------------------------------------------------
extern "C" void kernel_launch(void* const* d_in, const int* in_sizes, int n_in,
                              void* d_out, int out_size, void* d_ws, size_t ws_size,
                              hipStream_t stream) {
  const float* features = (const float*)d_in[0];
  const float* pos      = (const float*)d_in[1];
  const float* W_embed  = (const float*)d_in[2];
  const float* Wq       = (const float*)d_in[3];
  const float* Wk       = (const float*)d_in[4];
  const float* Wv       = (const float*)d_in[5];
  const float* P1       = (const float*)d_in[6];
  const float* P2       = (const float*)d_in[7];
  const float* G1       = (const float*)d_in[8];
  const float* G2       = (const float*)d_in[9];
  const float* Wo       = (const float*)d_in[10];
  const float* Wc1      = (const float*)d_in[11];
  const float* Wc2      = (const float*)d_in[12];
  float* out = (float*)d_out;

  // workspace layout (16B-aligned slices)
  float* x = (float*)d_ws;                                   // NPTS*Dh f32 (16 MB)
  unsigned short* qb = (unsigned short*)(x + (size_t)NPTS*Dh); // NPTS*Dh bf16 (8 MB)
  unsigned short* kb = qb + (size_t)NPTS*Dh;
  unsigned short* vb = kb + (size_t)NPTS*Dh;
  unsigned short* wT = vb + (size_t)NPTS*Dh;                 // 7*2*16384 bf16
  unsigned short* aggb = wT + 7*2*16384;                     // NPTS*Dh bf16 (8 MB)
  unsigned short* idxb = aggb + (size_t)NPTS*Dh;             // NPTS*KNN u16 (1 MB)

  // kNN partial indices (u16): aliased onto qb/kb (needs 8.4 MB); dead before qkv.
  unsigned short* pidx = qb;
  // pooled partials: aliased onto qb (dead after last fused layer).
  float* part = (float*)qb;

  unsigned short* QT  = wT + 0*32768;   // [2][128][128] each, transposed bf16
  unsigned short* KT  = wT + 1*32768;
  unsigned short* VT  = wT + 2*32768;
  unsigned short* P2T = wT + 3*32768;
  unsigned short* G1T = wT + 4*32768;
  unsigned short* G2T = wT + 5*32768;
  unsigned short* WoT = wT + 6*32768;

  knn_part_kernel<<<dim3(NN/256, NPART, BB), 256, 0, stream>>>(pos, pidx);
  knn_merge_kernel<<<NPTS/256, 256, 0, stream>>>(pos, pidx, idxb);

  wprep_all_kernel<<<dim3(64, 2, 7), 256, 0, stream>>>(Wq, Wk, Wv, P2, G1, G2, Wo, wT);
  embed_kernel<<<NPTS*Dh/256, 256, 0, stream>>>(features, W_embed, x);

  for (int l = 0; l < 2; l++) {
    qkv_kernel<<<NPTS/64, 256, 0, stream>>>(
        x, QT + l*16384, KT + l*16384, VT + l*16384, qb, kb, vb);
    fused_mega_kernel<<<256, 512, 0, stream>>>(
        qb, kb, vb, idxb, pos,
        P1 + l*3*Dh, P2T + l*16384, G1T + l*16384, G2T + l*16384, aggb);
    xupd_kernel<<<NPTS/64, 256, 0, stream>>>(x, aggb, WoT + l*16384);
  }

  pool_part_kernel<<<dim3(32, BB), 128, 0, stream>>>(x, part);
  head_kernel<<<BB, 128, 0, stream>>>(part, Wc1, Wc2, out);
}

// Round 6
// 944.626 us; speedup vs baseline: 7.3117x; 1.0534x over previous
//
#include <hip/hip_runtime.h>
#include <hip/hip_bf16.h>
#include <float.h>

// Problem constants
#define BB 8
#define NN 4096
#define KNN 16
#define Dh 128
#define NPTS (BB*NN)          // 32768
#define NPART 8               // kNN candidate partitions
#define PARTSZ (NN/NPART)     // 512

typedef __attribute__((ext_vector_type(8))) short bf16x8;   // 8 bf16 = 4 VGPRs
typedef __attribute__((ext_vector_type(8))) unsigned short u16x8;
typedef __attribute__((ext_vector_type(4))) float f32x4;    // MFMA 16x16 accumulator

#define MFMA16(a,b,c) __builtin_amdgcn_mfma_f32_16x16x32_bf16(a,b,c,0,0,0)

__device__ __forceinline__ unsigned short f2b(float f) {   // native RNE cvt
  __hip_bfloat16 h = __float2bfloat16(f);
  return *(unsigned short*)&h;
}
__device__ __forceinline__ unsigned pack_bf2(float lo, float hi) {
  __hip_bfloat16 l = __float2bfloat16(lo), h = __float2bfloat16(hi);
  return (unsigned)(*(unsigned short*)&l) | ((unsigned)(*(unsigned short*)&h) << 16);
}
__device__ __forceinline__ float b2f(unsigned short s) {
  union { unsigned u; float f; } v; v.u = ((unsigned)s) << 16; return v.f;
}
__device__ __forceinline__ float blo(unsigned u) {        // low bf16 of packed kv
  union { unsigned u; float f; } v; v.u = u << 16; return v.f;
}
__device__ __forceinline__ float bhi(unsigned u) {        // high bf16 of packed kv
  union { unsigned u; float f; } v; v.u = u & 0xffff0000u; return v.f;
}
__device__ __forceinline__ int swz16(int row) { return (row >> 2) << 4; } // trans-tile XOR

// ---------------------------------------------------------------------------
// x = relu(features @ W_embed)   [B*N,3] @ [3,128], f32 out
__global__ __launch_bounds__(256) void embed_kernel(
    const float* __restrict__ f, const float* __restrict__ We, float* __restrict__ x) {
  int i = blockIdx.x * 256 + threadIdx.x;
  if (i >= NPTS * Dh) return;
  int p = i >> 7, d = i & 127;
  float f0 = f[p*3+0], f1 = f[p*3+1], f2 = f[p*3+2];
  float v = f0 * We[0*Dh + d] + f1 * We[1*Dh + d] + f2 * We[2*Dh + d];
  x[i] = fmaxf(v, 0.f);
}

// ---------------------------------------------------------------------------
// kNN stage 1: per-partition top-16 with buffered-drain insert batching.
__global__ __launch_bounds__(256) void knn_part_kernel(
    const float* __restrict__ pos, unsigned short* __restrict__ pidx) {
  __shared__ float4 cand[PARTSZ];     // 8 KB
  int b = blockIdx.z, part = blockIdx.y;
  const float* pb = pos + (size_t)b * NN * 3;
  int c0 = part * PARTSZ;
  for (int i = threadIdx.x; i < PARTSZ; i += 256) {
    float X = pb[(c0+i)*3+0], Y = pb[(c0+i)*3+1], Z = pb[(c0+i)*3+2];
    cand[i] = make_float4(X, Y, Z, X*X + Y*Y + Z*Z);
  }
  __syncthreads();

  int q = blockIdx.x * 256 + threadIdx.x;
  float qx = pb[q*3+0], qy = pb[q*3+1], qz = pb[q*3+2];
  float qs = qx*qx + qy*qy + qz*qz;

  float val[KNN]; int ind[KNN];
  float cmax; int cslot;

  #pragma unroll
  for (int t = 0; t < KNN; t++) {
    float4 c = cand[t];
    val[t] = qs + c.w - 2.f*(qx*c.x + qy*c.y + qz*c.z);
    ind[t] = t;
  }
  cmax = val[0]; cslot = 0;
  #pragma unroll
  for (int i = 1; i < KNN; i++)
    if (val[i] >= cmax) { cmax = val[i]; cslot = i; }   // evict latest among ties

  float bv0 = 0.f, bv1 = 0.f, bv2 = 0.f, bv3 = 0.f;
  int   bi0 = 0,   bi1 = 0,   bi2 = 0,   bi3 = 0;
  int   cnt = 0;

#define DRAIN_SLOT(S, BV, BI)                                      \
  { bool act = ((S) < cnt) && ((BV) < cmax);                       \
    if (__ballot(act)) {                                           \
      _Pragma("unroll")                                            \
      for (int i = 0; i < KNN; i++) {                              \
        bool r = act && (i == cslot);                              \
        val[i] = r ? (BV) : val[i];                                \
        ind[i] = r ? (BI) : ind[i];                                \
      }                                                            \
      cmax = val[0]; cslot = 0;                                    \
      _Pragma("unroll")                                            \
      for (int i = 1; i < KNN; i++)                                \
        if (val[i] >= cmax) { cmax = val[i]; cslot = i; }          \
    } }
#define DRAIN_ALL                                                  \
  { DRAIN_SLOT(0, bv0, bi0) DRAIN_SLOT(1, bv1, bi1)                \
    DRAIN_SLOT(2, bv2, bi2) DRAIN_SLOT(3, bv3, bi3) cnt = 0; }

  for (int m = KNN; m < PARTSZ; m++) {
    float4 c = cand[m];
    float d2 = qs + c.w - 2.f*(qx*c.x + qy*c.y + qz*c.z);
    if (d2 < cmax) {
      bv0 = (cnt == 0) ? d2 : bv0;  bi0 = (cnt == 0) ? m : bi0;
      bv1 = (cnt == 1) ? d2 : bv1;  bi1 = (cnt == 1) ? m : bi1;
      bv2 = (cnt == 2) ? d2 : bv2;  bi2 = (cnt == 2) ? m : bi2;
      bv3 = (cnt == 3) ? d2 : bv3;  bi3 = (cnt == 3) ? m : bi3;
      cnt++;
    }
    if (__ballot(cnt == 4)) DRAIN_ALL
  }
  if (__ballot(cnt > 0)) DRAIN_ALL

#undef DRAIN_SLOT
#undef DRAIN_ALL

  size_t base = ((size_t)(b*NN + q) * NPART + part) * KNN;
  #pragma unroll
  for (int i = 0; i < KNN; i++) pidx[base + i] = (unsigned short)(b*NN + c0 + ind[i]);
}

// ---------------------------------------------------------------------------
// kNN stage 2: merge 8 partial top-16 lists -> final top-16.
__global__ __launch_bounds__(256) void knn_merge_kernel(
    const float* __restrict__ pos, const unsigned short* __restrict__ pidx,
    unsigned short* __restrict__ idxout) {
  int p = blockIdx.x * 256 + threadIdx.x;
  float qx = pos[p*3+0], qy = pos[p*3+1], qz = pos[p*3+2];
  float qs = qx*qx + qy*qy + qz*qz;

  float val[KNN]; int ind[KNN];
  #pragma unroll
  for (int i = 0; i < KNN; i++) { val[i] = FLT_MAX; ind[i] = 0; }
  float cmax = FLT_MAX; int cslot = 0;

  for (int t = 0; t < NPART*KNN; t++) {
    int j = pidx[(size_t)p*NPART*KNN + t];
    float X = pos[j*3+0], Y = pos[j*3+1], Z = pos[j*3+2];
    float sq = X*X + Y*Y + Z*Z;
    float d2 = qs + sq - 2.f*(qx*X + qy*Y + qz*Z);
    if (d2 < cmax) {
      #pragma unroll
      for (int i = 0; i < KNN; i++) if (i == cslot) { val[i] = d2; ind[i] = j; }
      cmax = val[0]; cslot = 0;
      #pragma unroll
      for (int i = 1; i < KNN; i++) if (val[i] >= cmax) { cmax = val[i]; cslot = i; }
    }
  }
  #pragma unroll
  for (int i = 0; i < KNN; i++) idxout[(size_t)p*KNN + i] = (unsigned short)ind[i];
}

// ---------------------------------------------------------------------------
// Weight prep: WT[z][l][o][i] = bf16(W[z][l][i][o])
__global__ __launch_bounds__(256) void wprep_all_kernel(
    const float* __restrict__ W0, const float* __restrict__ W1,
    const float* __restrict__ W2, const float* __restrict__ W3,
    const float* __restrict__ W4, const float* __restrict__ W5,
    const float* __restrict__ W6, unsigned short* __restrict__ wT) {
  const float* srcs[7] = {W0, W1, W2, W3, W4, W5, W6};
  int z = blockIdx.z, m = blockIdx.y;
  const float* W = srcs[z] + m*16384;
  unsigned short* WT = wT + z*32768 + m*16384;
  int t = blockIdx.x * 256 + threadIdx.x;
  int o = t >> 7, i = t & 127;
  WT[o*128 + i] = f2b(W[i*128 + o]);
}

// ---------------------------------------------------------------------------
// q / packed kv = x @ {Wq, Wk|Wv}. kv: u32 = {k lo16, v hi16} per (row,ch).
__global__ __launch_bounds__(256) void qkv_kernel(
    const float* __restrict__ x,
    const unsigned short* __restrict__ QT, const unsigned short* __restrict__ KT,
    const unsigned short* __restrict__ VT,
    unsigned short* __restrict__ qb, unsigned* __restrict__ kvb) {
  int w = threadIdx.x >> 6, l = threadIdx.x & 63;
  int lr = l & 15, lg = l >> 4;
  int R = blockIdx.x * 64 + w * 16;
  const float* xr = x + (size_t)(R + lr) * Dh + lg * 8;
  bf16x8 a[4];
  #pragma unroll
  for (int kt = 0; kt < 4; kt++) {
    bf16x8 av;
    #pragma unroll
    for (int j = 0; j < 8; j++) av[j] = (short)f2b(xr[kt*32 + j]);
    a[kt] = av;
  }
  #pragma unroll
  for (int n = 0; n < 8; n++) {
    f32x4 c = {0.f, 0.f, 0.f, 0.f};
    #pragma unroll
    for (int kt = 0; kt < 4; kt++)
      c = MFMA16(a[kt], *(const bf16x8*)&QT[(n*16 + lr)*Dh + kt*32 + lg*8], c);
    #pragma unroll
    for (int r = 0; r < 4; r++)
      qb[(size_t)(R + lg*4 + r)*Dh + n*16 + lr] = f2b(c[r]);
  }
  #pragma unroll
  for (int n = 0; n < 8; n++) {
    f32x4 ck = {0.f, 0.f, 0.f, 0.f}, cv = {0.f, 0.f, 0.f, 0.f};
    #pragma unroll
    for (int kt = 0; kt < 4; kt++) {
      ck = MFMA16(a[kt], *(const bf16x8*)&KT[(n*16 + lr)*Dh + kt*32 + lg*8], ck);
      cv = MFMA16(a[kt], *(const bf16x8*)&VT[(n*16 + lr)*Dh + kt*32 + lg*8], cv);
    }
    #pragma unroll
    for (int r = 0; r < 4; r++)
      kvb[(size_t)(R + lg*4 + r)*Dh + n*16 + lr] = pack_bf2(ck[r], cv[r]);
  }
}

// ---------------------------------------------------------------------------
// per-point prefetch context (registers only)
struct PtCtx {
  int jA, jC[4];
  float rx, ry, rz;
  unsigned short qv[8];
};
__device__ __forceinline__ void load_ctx(PtCtx& c, int p,
    const unsigned short* __restrict__ idxb, const float* __restrict__ pos,
    const unsigned short* __restrict__ qb, int lr, int lg) {
  c.jA = idxb[(size_t)p*KNN + lr];
  #pragma unroll
  for (int r = 0; r < 4; r++) c.jC[r] = idxb[(size_t)p*KNN + lg*4 + r];
  float px0 = pos[p*3+0], py0 = pos[p*3+1], pz0 = pos[p*3+2];
  c.rx = px0 - pos[c.jA*3+0];
  c.ry = py0 - pos[c.jA*3+1];
  c.rz = pz0 - pos[c.jA*3+2];
  #pragma unroll
  for (int n = 0; n < 8; n++) c.qv[n] = qb[(size_t)p*Dh + n*16 + lr];
}

// ---------------------------------------------------------------------------
// Mega fused vector-attention block. 256 blocks (1/CU) x 512 thr (8 waves).
// Weights P2T/G1T/G2T staged in LDS (swizzled); each wave runs 16 points.
// Per point: burst-issue kv gathers -> t1/delta (hides latency) -> g ->
// G1 -> G2 -> softmax/agg. Next point's idx/pos/q prefetched one iter ahead.
__global__ __launch_bounds__(512, 2) void fused_mega_kernel(
    const unsigned short* __restrict__ qb, const unsigned* __restrict__ kvb,
    const unsigned short* __restrict__ idxb, const float* __restrict__ pos,
    const float* __restrict__ P1,
    const unsigned short* __restrict__ P2T, const unsigned short* __restrict__ G1T,
    const unsigned short* __restrict__ G2T, unsigned short* __restrict__ aggb) {
  __shared__ __align__(16) unsigned short wB[3][16384];    // 96 KB, swizzled
  __shared__ __align__(16) unsigned short trans[8][2048];  // 32 KB (4 KB/wave)
  int tid = threadIdx.x;
  int wv = tid >> 6, l = tid & 63;
  int lr = l & 15, lg = l >> 4;
  const int swz = (lr & 7) << 3;        // weight-LDS read swizzle (u16)
  const int swtR = swz16(lr);           // trans-tile read swizzle (row=lr)

  {
    const unsigned short* srcs[3] = {P2T, G1T, G2T};
    #pragma unroll
    for (int z = 0; z < 3; z++) {
      const unsigned short* src = srcs[z];
      for (int t = tid * 8; t < 16384; t += 512 * 8) {
        int dst = t ^ (((t >> 7) & 7) << 3);
        *(u16x8*)&wB[z][dst] = *(const u16x8*)&src[t];
      }
    }
  }
  __syncthreads();

  unsigned short* tb = trans[wv];
  int p0 = blockIdx.x * 128 + wv * 16;

  PtCtx cur, nxt;
  load_ctx(cur, p0, idxb, pos, qb, lr, lg);
  nxt = cur;

  #pragma unroll 1
  for (int i = 0; i < 16; i++) {
    int p = p0 + i;

    // ---- burst-issue all 32 packed kv gathers for THIS point (used later)
    const unsigned* kvp0 = kvb + (size_t)cur.jC[0]*Dh;
    const unsigned* kvp1 = kvb + (size_t)cur.jC[1]*Dh;
    const unsigned* kvp2 = kvb + (size_t)cur.jC[2]*Dh;
    const unsigned* kvp3 = kvb + (size_t)cur.jC[3]*Dh;
    unsigned kvr[8][4];
    #pragma unroll
    for (int n = 0; n < 8; n++) {
      kvr[n][0] = kvp0[n*16 + lr];
      kvr[n][1] = kvp1[n*16 + lr];
      kvr[n][2] = kvp2[n*16 + lr];
      kvr[n][3] = kvp3[n*16 + lr];
    }

    // ---- prefetch next point's ctx (consumed next iteration)
    if (i < 15) load_ctx(nxt, p + 1, idxb, pos, qb, lr, lg);

    // ---- t1 = relu(rel @ P1) in A-frag layout; float4 P1 loads (L1-hot)
    bf16x8 aT[4];
    #pragma unroll
    for (int kt = 0; kt < 4; kt++) {
      int c0 = kt*32 + lg*8;
      float4 pa0 = *(const float4*)&P1[c0],        pa1 = *(const float4*)&P1[c0+4];
      float4 pb0 = *(const float4*)&P1[Dh+c0],     pb1 = *(const float4*)&P1[Dh+c0+4];
      float4 pc0 = *(const float4*)&P1[2*Dh+c0],   pc1 = *(const float4*)&P1[2*Dh+c0+4];
      bf16x8 av;
      av[0] = (short)f2b(fmaxf(cur.rx*pa0.x + cur.ry*pb0.x + cur.rz*pc0.x, 0.f));
      av[1] = (short)f2b(fmaxf(cur.rx*pa0.y + cur.ry*pb0.y + cur.rz*pc0.y, 0.f));
      av[2] = (short)f2b(fmaxf(cur.rx*pa0.z + cur.ry*pb0.z + cur.rz*pc0.z, 0.f));
      av[3] = (short)f2b(fmaxf(cur.rx*pa0.w + cur.ry*pb0.w + cur.rz*pc0.w, 0.f));
      av[4] = (short)f2b(fmaxf(cur.rx*pa1.x + cur.ry*pb1.x + cur.rz*pc1.x, 0.f));
      av[5] = (short)f2b(fmaxf(cur.rx*pa1.y + cur.ry*pb1.y + cur.rz*pc1.y, 0.f));
      av[6] = (short)f2b(fmaxf(cur.rx*pa1.z + cur.ry*pb1.z + cur.rz*pc1.z, 0.f));
      av[7] = (short)f2b(fmaxf(cur.rx*pa1.w + cur.ry*pb1.w + cur.rz*pc1.w, 0.f));
      aT[kt] = av;
    }

    // ---- DELTA = t1 @ P2 (C-layout regs, f32)
    f32x4 dlt[8];
    #pragma unroll
    for (int n = 0; n < 8; n++) {
      f32x4 c = {0.f, 0.f, 0.f, 0.f};
      #pragma unroll
      for (int kt = 0; kt < 4; kt++)
        c = MFMA16(aT[kt], *(const bf16x8*)&wB[0][((n*16 + lr)*Dh + kt*32 + lg*8) ^ swz], c);
      dlt[n] = c;
    }

    // ---- g = q - kj + delta -> swizzled trans tile (C-layout scatter)
    #pragma unroll
    for (int n = 0; n < 8; n++) {
      float q = b2f(cur.qv[n]);
      #pragma unroll
      for (int r = 0; r < 4; r++) {
        int row = lg*4 + r, ch = n*16 + lr;
        tb[(row*Dh + ch) ^ swz16(row)] = f2b(q - blo(kvr[n][r]) + dlt[n][r]);
      }
    }

    // ---- H = relu(g @ G1)
    bf16x8 ag[4];
    #pragma unroll
    for (int kt = 0; kt < 4; kt++)
      ag[kt] = *(const bf16x8*)&tb[(lr*Dh + kt*32 + lg*8) ^ swtR];
    f32x4 hh[8];
    #pragma unroll
    for (int n = 0; n < 8; n++) {
      f32x4 c = {0.f, 0.f, 0.f, 0.f};
      #pragma unroll
      for (int kt = 0; kt < 4; kt++)
        c = MFMA16(ag[kt], *(const bf16x8*)&wB[1][((n*16 + lr)*Dh + kt*32 + lg*8) ^ swz], c);
      hh[n] = c;
    }
    #pragma unroll
    for (int n = 0; n < 8; n++) {
      #pragma unroll
      for (int r = 0; r < 4; r++) {
        int row = lg*4 + r, ch = n*16 + lr;
        tb[(row*Dh + ch) ^ swz16(row)] = f2b(fmaxf(hh[n][r], 0.f));
      }
    }

    // ---- LOGITS = H @ G2
    bf16x8 ah[4];
    #pragma unroll
    for (int kt = 0; kt < 4; kt++)
      ah[kt] = *(const bf16x8*)&tb[(lr*Dh + kt*32 + lg*8) ^ swtR];
    f32x4 lgt[8];
    #pragma unroll
    for (int n = 0; n < 8; n++) {
      f32x4 c = {0.f, 0.f, 0.f, 0.f};
      #pragma unroll
      for (int kt = 0; kt < 4; kt++)
        c = MFMA16(ah[kt], *(const bf16x8*)&wB[2][((n*16 + lr)*Dh + kt*32 + lg*8) ^ swz], c);
      lgt[n] = c;
    }

    // ---- softmax over 16 neighbors + agg = sum attn*(v+delta)
    #pragma unroll
    for (int n = 0; n < 8; n++) {
      f32x4 L = lgt[n];
      float m = fmaxf(fmaxf(L[0], L[1]), fmaxf(L[2], L[3]));
      m = fmaxf(m, __shfl_xor(m, 16));
      m = fmaxf(m, __shfl_xor(m, 32));
      float e0 = __expf(L[0]-m), e1 = __expf(L[1]-m);
      float e2 = __expf(L[2]-m), e3 = __expf(L[3]-m);
      float s = e0 + e1 + e2 + e3;
      s += __shfl_xor(s, 16);
      s += __shfl_xor(s, 32);
      float inv = 1.f / s;
      float ws;
      ws  = e0 * (bhi(kvr[n][0]) + dlt[n][0]);
      ws += e1 * (bhi(kvr[n][1]) + dlt[n][1]);
      ws += e2 * (bhi(kvr[n][2]) + dlt[n][2]);
      ws += e3 * (bhi(kvr[n][3]) + dlt[n][3]);
      ws *= inv;
      ws += __shfl_xor(ws, 16);
      ws += __shfl_xor(ws, 32);
      if (lg == 0) aggb[(size_t)p*Dh + n*16 + lr] = f2b(ws);
    }

    cur = nxt;
  }
}

// ---------------------------------------------------------------------------
// x += aggb @ Wo : [32768,128]@[128,128], f32 accumulate into x.
__global__ __launch_bounds__(256) void xupd_kernel(
    float* __restrict__ x, const unsigned short* __restrict__ aggb,
    const unsigned short* __restrict__ WoT) {
  int w = threadIdx.x >> 6, l = threadIdx.x & 63;
  int lr = l & 15, lg = l >> 4;
  int R = blockIdx.x * 64 + w * 16;
  bf16x8 a[4];
  #pragma unroll
  for (int kt = 0; kt < 4; kt++)
    a[kt] = *(const bf16x8*)&aggb[(size_t)(R + lr)*Dh + kt*32 + lg*8];
  #pragma unroll
  for (int n = 0; n < 8; n++) {
    f32x4 c = {0.f, 0.f, 0.f, 0.f};
    #pragma unroll
    for (int kt = 0; kt < 4; kt++)
      c = MFMA16(a[kt], *(const bf16x8*)&WoT[(n*16 + lr)*Dh + kt*32 + lg*8], c);
    #pragma unroll
    for (int r = 0; r < 4; r++)
      x[(size_t)(R + lg*4 + r)*Dh + n*16 + lr] += c[r];
  }
}

// ---------------------------------------------------------------------------
// Global max-pool + classifier head (f32)
__global__ __launch_bounds__(128) void pool_part_kernel(
    const float* __restrict__ x, float* __restrict__ part) {
  int b = blockIdx.y, chunk = blockIdx.x, d = threadIdx.x;
  const float* xb = x + ((size_t)b*NN + chunk*128) * Dh;
  float m = -FLT_MAX;
  for (int n = 0; n < 128; n++) m = fmaxf(m, xb[(size_t)n*Dh + d]);
  part[(b*32 + chunk)*Dh + d] = m;
}

__global__ __launch_bounds__(128) void head_kernel(
    const float* __restrict__ part, const float* __restrict__ W1,
    const float* __restrict__ W2, float* __restrict__ out) {
  int b = blockIdx.x, d = threadIdx.x;
  __shared__ float pooled[Dh], h[Dh];
  float m = -FLT_MAX;
  for (int c = 0; c < 32; c++) m = fmaxf(m, part[(b*32 + c)*Dh + d]);
  pooled[d] = m;
  __syncthreads();
  float acc = 0.f;
  for (int c = 0; c < Dh; c++) acc += pooled[c] * W1[c*Dh + d];
  h[d] = fmaxf(acc, 0.f);
  __syncthreads();
  if (d < 40) {
    float o = 0.f;
    for (int c = 0; c < Dh; c++) o += h[c] * W2[c*40 + d];
    out[b*40 + d] = o;
  }
}

// ---------------------------------------------------------------------------
extern "C" void kernel_launch(void* const* d_in, const int* in_sizes, int n_in,
                              void* d_out, int out_size, void* d_ws, size_t ws_size,
                              hipStream_t stream) {
  const float* features = (const float*)d_in[0];
  const float* pos      = (const float*)d_in[1];
  const float* W_embed  = (const float*)d_in[2];
  const float* Wq       = (const float*)d_in[3];
  const float* Wk       = (const float*)d_in[4];
  const float* Wv       = (const float*)d_in[5];
  const float* P1       = (const float*)d_in[6];
  const float* P2       = (const float*)d_in[7];
  const float* G1       = (const float*)d_in[8];
  const float* G2       = (const float*)d_in[9];
  const float* Wo       = (const float*)d_in[10];
  const float* Wc1      = (const float*)d_in[11];
  const float* Wc2      = (const float*)d_in[12];
  float* out = (float*)d_out;

  // workspace layout (16B-aligned slices)
  float* x = (float*)d_ws;                                     // NPTS*Dh f32 (16 MB)
  unsigned short* qb = (unsigned short*)(x + (size_t)NPTS*Dh); // NPTS*Dh bf16 (8 MB)
  unsigned* kvb = (unsigned*)(qb + (size_t)NPTS*Dh);           // NPTS*Dh u32 (16 MB)
  unsigned short* wT = (unsigned short*)(kvb + (size_t)NPTS*Dh); // 7*2*16384 bf16
  unsigned short* aggb = wT + 7*2*16384;                       // NPTS*Dh bf16 (8 MB)
  unsigned short* idxb = aggb + (size_t)NPTS*Dh;               // NPTS*KNN u16 (1 MB)

  // kNN partial indices (u16): aliased onto kvb (needs 8.4 MB of 16); dead before qkv.
  unsigned short* pidx = (unsigned short*)kvb;
  // pooled partials: aliased onto qb (dead after last fused layer).
  float* part = (float*)qb;

  unsigned short* QT  = wT + 0*32768;   // [2][128][128] each, transposed bf16
  unsigned short* KT  = wT + 1*32768;
  unsigned short* VT  = wT + 2*32768;
  unsigned short* P2T = wT + 3*32768;
  unsigned short* G1T = wT + 4*32768;
  unsigned short* G2T = wT + 5*32768;
  unsigned short* WoT = wT + 6*32768;

  knn_part_kernel<<<dim3(NN/256, NPART, BB), 256, 0, stream>>>(pos, pidx);
  knn_merge_kernel<<<NPTS/256, 256, 0, stream>>>(pos, pidx, idxb);

  wprep_all_kernel<<<dim3(64, 2, 7), 256, 0, stream>>>(Wq, Wk, Wv, P2, G1, G2, Wo, wT);
  embed_kernel<<<NPTS*Dh/256, 256, 0, stream>>>(features, W_embed, x);

  for (int l = 0; l < 2; l++) {
    qkv_kernel<<<NPTS/64, 256, 0, stream>>>(
        x, QT + l*16384, KT + l*16384, VT + l*16384, qb, kvb);
    fused_mega_kernel<<<256, 512, 0, stream>>>(
        qb, kvb, idxb, pos,
        P1 + l*3*Dh, P2T + l*16384, G1T + l*16384, G2T + l*16384, aggb);
    xupd_kernel<<<NPTS/64, 256, 0, stream>>>(x, aggb, WoT + l*16384);
  }

  pool_part_kernel<<<dim3(32, BB), 128, 0, stream>>>(x, part);
  head_kernel<<<BB, 128, 0, stream>>>(part, Wc1, Wc2, out);
}

// Round 8
// 937.044 us; speedup vs baseline: 7.3709x; 1.0081x over previous
//
#include <hip/hip_runtime.h>
#include <hip/hip_bf16.h>
#include <float.h>

// Problem constants
#define BB 8
#define NN 4096
#define KNN 16
#define Dh 128
#define NPTS (BB*NN)          // 32768
#define NPART 8               // kNN candidate partitions
#define PARTSZ (NN/NPART)     // 512

typedef __attribute__((ext_vector_type(8))) short bf16x8;   // 8 bf16 = 4 VGPRs
typedef __attribute__((ext_vector_type(8))) unsigned short u16x8;
typedef __attribute__((ext_vector_type(4))) float f32x4;    // MFMA 16x16 accumulator

#define MFMA16(a,b,c) __builtin_amdgcn_mfma_f32_16x16x32_bf16(a,b,c,0,0,0)

__device__ __forceinline__ unsigned short f2b(float f) {   // native RNE cvt
  __hip_bfloat16 h = __float2bfloat16(f);
  return *(unsigned short*)&h;
}
__device__ __forceinline__ unsigned pack_bf2(float lo, float hi) {
  __hip_bfloat16 l = __float2bfloat16(lo), h = __float2bfloat16(hi);
  return (unsigned)(*(unsigned short*)&l) | ((unsigned)(*(unsigned short*)&h) << 16);
}
__device__ __forceinline__ float b2f(unsigned short s) {
  union { unsigned u; float f; } v; v.u = ((unsigned)s) << 16; return v.f;
}
__device__ __forceinline__ float blo(unsigned u) {        // low bf16 of packed kv
  union { unsigned u; float f; } v; v.u = u << 16; return v.f;
}
__device__ __forceinline__ float bhi(unsigned u) {        // high bf16 of packed kv
  union { unsigned u; float f; } v; v.u = u & 0xffff0000u; return v.f;
}
__device__ __forceinline__ int swz16(int row) { return (row >> 2) << 4; } // trans-tile XOR

// ---------------------------------------------------------------------------
// x = relu(features @ W_embed)   [B*N,3] @ [3,128], f32 out
__global__ __launch_bounds__(256) void embed_kernel(
    const float* __restrict__ f, const float* __restrict__ We, float* __restrict__ x) {
  int i = blockIdx.x * 256 + threadIdx.x;
  if (i >= NPTS * Dh) return;
  int p = i >> 7, d = i & 127;
  float f0 = f[p*3+0], f1 = f[p*3+1], f2 = f[p*3+2];
  float v = f0 * We[0*Dh + d] + f1 * We[1*Dh + d] + f2 * We[2*Dh + d];
  x[i] = fmaxf(v, 0.f);
}

// ---------------------------------------------------------------------------
// kNN stage 1: per-partition top-16 with buffered-drain insert batching.
__global__ __launch_bounds__(256) void knn_part_kernel(
    const float* __restrict__ pos, unsigned short* __restrict__ pidx) {
  __shared__ float4 cand[PARTSZ];     // 8 KB
  int b = blockIdx.z, part = blockIdx.y;
  const float* pb = pos + (size_t)b * NN * 3;
  int c0 = part * PARTSZ;
  for (int i = threadIdx.x; i < PARTSZ; i += 256) {
    float X = pb[(c0+i)*3+0], Y = pb[(c0+i)*3+1], Z = pb[(c0+i)*3+2];
    cand[i] = make_float4(X, Y, Z, X*X + Y*Y + Z*Z);
  }
  __syncthreads();

  int q = blockIdx.x * 256 + threadIdx.x;
  float qx = pb[q*3+0], qy = pb[q*3+1], qz = pb[q*3+2];
  float qs = qx*qx + qy*qy + qz*qz;

  float val[KNN]; int ind[KNN];
  float cmax; int cslot;

  #pragma unroll
  for (int t = 0; t < KNN; t++) {
    float4 c = cand[t];
    val[t] = qs + c.w - 2.f*(qx*c.x + qy*c.y + qz*c.z);
    ind[t] = t;
  }
  cmax = val[0]; cslot = 0;
  #pragma unroll
  for (int i = 1; i < KNN; i++)
    if (val[i] >= cmax) { cmax = val[i]; cslot = i; }   // evict latest among ties

  float bv0 = 0.f, bv1 = 0.f, bv2 = 0.f, bv3 = 0.f;
  int   bi0 = 0,   bi1 = 0,   bi2 = 0,   bi3 = 0;
  int   cnt = 0;

#define DRAIN_SLOT(S, BV, BI)                                      \
  { bool act = ((S) < cnt) && ((BV) < cmax);                       \
    if (__ballot(act)) {                                           \
      _Pragma("unroll")                                            \
      for (int i = 0; i < KNN; i++) {                              \
        bool r = act && (i == cslot);                              \
        val[i] = r ? (BV) : val[i];                                \
        ind[i] = r ? (BI) : ind[i];                                \
      }                                                            \
      cmax = val[0]; cslot = 0;                                    \
      _Pragma("unroll")                                            \
      for (int i = 1; i < KNN; i++)                                \
        if (val[i] >= cmax) { cmax = val[i]; cslot = i; }          \
    } }
#define DRAIN_ALL                                                  \
  { DRAIN_SLOT(0, bv0, bi0) DRAIN_SLOT(1, bv1, bi1)                \
    DRAIN_SLOT(2, bv2, bi2) DRAIN_SLOT(3, bv3, bi3) cnt = 0; }

  for (int m = KNN; m < PARTSZ; m++) {
    float4 c = cand[m];
    float d2 = qs + c.w - 2.f*(qx*c.x + qy*c.y + qz*c.z);
    if (d2 < cmax) {
      bv0 = (cnt == 0) ? d2 : bv0;  bi0 = (cnt == 0) ? m : bi0;
      bv1 = (cnt == 1) ? d2 : bv1;  bi1 = (cnt == 1) ? m : bi1;
      bv2 = (cnt == 2) ? d2 : bv2;  bi2 = (cnt == 2) ? m : bi2;
      bv3 = (cnt == 3) ? d2 : bv3;  bi3 = (cnt == 3) ? m : bi3;
      cnt++;
    }
    if (__ballot(cnt == 4)) DRAIN_ALL
  }
  if (__ballot(cnt > 0)) DRAIN_ALL

#undef DRAIN_SLOT
#undef DRAIN_ALL

  size_t base = ((size_t)(b*NN + q) * NPART + part) * KNN;
  #pragma unroll
  for (int i = 0; i < KNN; i++) pidx[base + i] = (unsigned short)(b*NN + c0 + ind[i]);
}

// ---------------------------------------------------------------------------
// kNN stage 2: merge 8 partial top-16 lists -> final top-16.
__global__ __launch_bounds__(256) void knn_merge_kernel(
    const float* __restrict__ pos, const unsigned short* __restrict__ pidx,
    unsigned short* __restrict__ idxout) {
  int p = blockIdx.x * 256 + threadIdx.x;
  float qx = pos[p*3+0], qy = pos[p*3+1], qz = pos[p*3+2];
  float qs = qx*qx + qy*qy + qz*qz;

  float val[KNN]; int ind[KNN];
  #pragma unroll
  for (int i = 0; i < KNN; i++) { val[i] = FLT_MAX; ind[i] = 0; }
  float cmax = FLT_MAX; int cslot = 0;

  for (int t = 0; t < NPART*KNN; t++) {
    int j = pidx[(size_t)p*NPART*KNN + t];
    float X = pos[j*3+0], Y = pos[j*3+1], Z = pos[j*3+2];
    float sq = X*X + Y*Y + Z*Z;
    float d2 = qs + sq - 2.f*(qx*X + qy*Y + qz*Z);
    if (d2 < cmax) {
      #pragma unroll
      for (int i = 0; i < KNN; i++) if (i == cslot) { val[i] = d2; ind[i] = j; }
      cmax = val[0]; cslot = 0;
      #pragma unroll
      for (int i = 1; i < KNN; i++) if (val[i] >= cmax) { cmax = val[i]; cslot = i; }
    }
  }
  #pragma unroll
  for (int i = 0; i < KNN; i++) idxout[(size_t)p*KNN + i] = (unsigned short)ind[i];
}

// ---------------------------------------------------------------------------
// Weight prep: WT[z][l][o][i] = bf16(W[z][l][i][o])
__global__ __launch_bounds__(256) void wprep_all_kernel(
    const float* __restrict__ W0, const float* __restrict__ W1,
    const float* __restrict__ W2, const float* __restrict__ W3,
    const float* __restrict__ W4, const float* __restrict__ W5,
    const float* __restrict__ W6, unsigned short* __restrict__ wT) {
  const float* srcs[7] = {W0, W1, W2, W3, W4, W5, W6};
  int z = blockIdx.z, m = blockIdx.y;
  const float* W = srcs[z] + m*16384;
  unsigned short* WT = wT + z*32768 + m*16384;
  int t = blockIdx.x * 256 + threadIdx.x;
  int o = t >> 7, i = t & 127;
  WT[o*128 + i] = f2b(W[i*128 + o]);
}

// ---------------------------------------------------------------------------
// q / packed kv = x @ {Wq, Wk|Wv}. kv: u32 = {k lo16, v hi16} per (row,ch).
__global__ __launch_bounds__(256) void qkv_kernel(
    const float* __restrict__ x,
    const unsigned short* __restrict__ QT, const unsigned short* __restrict__ KT,
    const unsigned short* __restrict__ VT,
    unsigned short* __restrict__ qb, unsigned* __restrict__ kvb) {
  int w = threadIdx.x >> 6, l = threadIdx.x & 63;
  int lr = l & 15, lg = l >> 4;
  int R = blockIdx.x * 64 + w * 16;
  const float* xr = x + (size_t)(R + lr) * Dh + lg * 8;
  bf16x8 a[4];
  #pragma unroll
  for (int kt = 0; kt < 4; kt++) {
    bf16x8 av;
    #pragma unroll
    for (int j = 0; j < 8; j++) av[j] = (short)f2b(xr[kt*32 + j]);
    a[kt] = av;
  }
  #pragma unroll
  for (int n = 0; n < 8; n++) {
    f32x4 c = {0.f, 0.f, 0.f, 0.f};
    #pragma unroll
    for (int kt = 0; kt < 4; kt++)
      c = MFMA16(a[kt], *(const bf16x8*)&QT[(n*16 + lr)*Dh + kt*32 + lg*8], c);
    #pragma unroll
    for (int r = 0; r < 4; r++)
      qb[(size_t)(R + lg*4 + r)*Dh + n*16 + lr] = f2b(c[r]);
  }
  #pragma unroll
  for (int n = 0; n < 8; n++) {
    f32x4 ck = {0.f, 0.f, 0.f, 0.f}, cv = {0.f, 0.f, 0.f, 0.f};
    #pragma unroll
    for (int kt = 0; kt < 4; kt++) {
      ck = MFMA16(a[kt], *(const bf16x8*)&KT[(n*16 + lr)*Dh + kt*32 + lg*8], ck);
      cv = MFMA16(a[kt], *(const bf16x8*)&VT[(n*16 + lr)*Dh + kt*32 + lg*8], cv);
    }
    #pragma unroll
    for (int r = 0; r < 4; r++)
      kvb[(size_t)(R + lg*4 + r)*Dh + n*16 + lr] = pack_bf2(ck[r], cv[r]);
  }
}

// ---------------------------------------------------------------------------
// per-point prefetch context (registers only)
struct PtCtx {
  int jA, jC[4];
  float rx, ry, rz;
  unsigned short qv[8];
};
__device__ __forceinline__ void load_ctx(PtCtx& c, int p,
    const unsigned short* __restrict__ idxb, const float* __restrict__ pos,
    const unsigned short* __restrict__ qb, int lr, int lg) {
  c.jA = idxb[(size_t)p*KNN + lr];
  #pragma unroll
  for (int r = 0; r < 4; r++) c.jC[r] = idxb[(size_t)p*KNN + lg*4 + r];
  float px0 = pos[p*3+0], py0 = pos[p*3+1], pz0 = pos[p*3+2];
  c.rx = px0 - pos[c.jA*3+0];
  c.ry = py0 - pos[c.jA*3+1];
  c.rz = pz0 - pos[c.jA*3+2];
  #pragma unroll
  for (int n = 0; n < 8; n++) c.qv[n] = qb[(size_t)p*Dh + n*16 + lr];
}

// ---------------------------------------------------------------------------
// Mega fused vector-attention block. 256 blocks (1/CU) x 512 thr (8 waves).
// XCD-swizzled so all 32 blocks of one batch land on one XCD: that batch's
// kvb slice (2 MB) fits its 4 MB L2 -> scattered kv gathers become L2 hits.
// amdgpu_waves_per_eu(2): LDS caps us at 2 waves/SIMD anyway; allow 256 VGPRs
// so the kv burst + ctx prefetch live in registers (round-6 spill fix).
__global__ void __attribute__((amdgpu_flat_work_group_size(512, 512)))
__attribute__((amdgpu_waves_per_eu(2)))
fused_mega_kernel(
    const unsigned short* __restrict__ qb, const unsigned* __restrict__ kvb,
    const unsigned short* __restrict__ idxb, const float* __restrict__ pos,
    const float* __restrict__ P1,
    const unsigned short* __restrict__ P2T, const unsigned short* __restrict__ G1T,
    const unsigned short* __restrict__ G2T, unsigned short* __restrict__ aggb) {
  __shared__ __align__(16) unsigned short wB[3][16384];    // 96 KB, swizzled
  __shared__ __align__(16) unsigned short trans[8][2048];  // 32 KB (4 KB/wave)
  int tid = threadIdx.x;
  int wv = tid >> 6, l = tid & 63;
  int lr = l & 15, lg = l >> 4;
  const int swz = (lr & 7) << 3;        // weight-LDS read swizzle (u16)
  const int swtR = swz16(lr);           // trans-tile read swizzle (row=lr)

  // XCD swizzle: hardware XCD = blockIdx.x % 8. Map so batch b's 32 blocks
  // all have blockIdx.x % 8 == b.
  int orig = (blockIdx.x & 7) * 32 + (blockIdx.x >> 3);

  {
    const unsigned short* srcs[3] = {P2T, G1T, G2T};
    #pragma unroll
    for (int z = 0; z < 3; z++) {
      const unsigned short* src = srcs[z];
      for (int t = tid * 8; t < 16384; t += 512 * 8) {
        int dst = t ^ (((t >> 7) & 7) << 3);
        *(u16x8*)&wB[z][dst] = *(const u16x8*)&src[t];
      }
    }
  }
  __syncthreads();

  unsigned short* tb = trans[wv];
  int p0 = orig * 128 + wv * 16;

  PtCtx cur, nxt;
  load_ctx(cur, p0, idxb, pos, qb, lr, lg);
  nxt = cur;

  #pragma unroll 1
  for (int i = 0; i < 16; i++) {
    int p = p0 + i;

    // ---- burst-issue all 32 packed kv gathers for THIS point (used later)
    const unsigned* kvp0 = kvb + (size_t)cur.jC[0]*Dh;
    const unsigned* kvp1 = kvb + (size_t)cur.jC[1]*Dh;
    const unsigned* kvp2 = kvb + (size_t)cur.jC[2]*Dh;
    const unsigned* kvp3 = kvb + (size_t)cur.jC[3]*Dh;
    unsigned kvr[8][4];
    #pragma unroll
    for (int n = 0; n < 8; n++) {
      kvr[n][0] = kvp0[n*16 + lr];
      kvr[n][1] = kvp1[n*16 + lr];
      kvr[n][2] = kvp2[n*16 + lr];
      kvr[n][3] = kvp3[n*16 + lr];
    }

    // ---- prefetch next point's ctx (consumed next iteration)
    if (i < 15) load_ctx(nxt, p + 1, idxb, pos, qb, lr, lg);

    // ---- t1 = relu(rel @ P1) in A-frag layout; float4 P1 loads (L1-hot)
    bf16x8 aT[4];
    #pragma unroll
    for (int kt = 0; kt < 4; kt++) {
      int c0 = kt*32 + lg*8;
      float4 pa0 = *(const float4*)&P1[c0],        pa1 = *(const float4*)&P1[c0+4];
      float4 pb0 = *(const float4*)&P1[Dh+c0],     pb1 = *(const float4*)&P1[Dh+c0+4];
      float4 pc0 = *(const float4*)&P1[2*Dh+c0],   pc1 = *(const float4*)&P1[2*Dh+c0+4];
      bf16x8 av;
      av[0] = (short)f2b(fmaxf(cur.rx*pa0.x + cur.ry*pb0.x + cur.rz*pc0.x, 0.f));
      av[1] = (short)f2b(fmaxf(cur.rx*pa0.y + cur.ry*pb0.y + cur.rz*pc0.y, 0.f));
      av[2] = (short)f2b(fmaxf(cur.rx*pa0.z + cur.ry*pb0.z + cur.rz*pc0.z, 0.f));
      av[3] = (short)f2b(fmaxf(cur.rx*pa0.w + cur.ry*pb0.w + cur.rz*pc0.w, 0.f));
      av[4] = (short)f2b(fmaxf(cur.rx*pa1.x + cur.ry*pb1.x + cur.rz*pc1.x, 0.f));
      av[5] = (short)f2b(fmaxf(cur.rx*pa1.y + cur.ry*pb1.y + cur.rz*pc1.y, 0.f));
      av[6] = (short)f2b(fmaxf(cur.rx*pa1.z + cur.ry*pb1.z + cur.rz*pc1.z, 0.f));
      av[7] = (short)f2b(fmaxf(cur.rx*pa1.w + cur.ry*pb1.w + cur.rz*pc1.w, 0.f));
      aT[kt] = av;
    }

    // ---- DELTA = t1 @ P2 (C-layout regs, f32)
    f32x4 dlt[8];
    #pragma unroll
    for (int n = 0; n < 8; n++) {
      f32x4 c = {0.f, 0.f, 0.f, 0.f};
      #pragma unroll
      for (int kt = 0; kt < 4; kt++)
        c = MFMA16(aT[kt], *(const bf16x8*)&wB[0][((n*16 + lr)*Dh + kt*32 + lg*8) ^ swz], c);
      dlt[n] = c;
    }

    // ---- g = q - kj + delta -> swizzled trans tile (C-layout scatter)
    #pragma unroll
    for (int n = 0; n < 8; n++) {
      float q = b2f(cur.qv[n]);
      #pragma unroll
      for (int r = 0; r < 4; r++) {
        int row = lg*4 + r, ch = n*16 + lr;
        tb[(row*Dh + ch) ^ swz16(row)] = f2b(q - blo(kvr[n][r]) + dlt[n][r]);
      }
    }

    // ---- H = relu(g @ G1)
    bf16x8 ag[4];
    #pragma unroll
    for (int kt = 0; kt < 4; kt++)
      ag[kt] = *(const bf16x8*)&tb[(lr*Dh + kt*32 + lg*8) ^ swtR];
    f32x4 hh[8];
    #pragma unroll
    for (int n = 0; n < 8; n++) {
      f32x4 c = {0.f, 0.f, 0.f, 0.f};
      #pragma unroll
      for (int kt = 0; kt < 4; kt++)
        c = MFMA16(ag[kt], *(const bf16x8*)&wB[1][((n*16 + lr)*Dh + kt*32 + lg*8) ^ swz], c);
      hh[n] = c;
    }
    #pragma unroll
    for (int n = 0; n < 8; n++) {
      #pragma unroll
      for (int r = 0; r < 4; r++) {
        int row = lg*4 + r, ch = n*16 + lr;
        tb[(row*Dh + ch) ^ swz16(row)] = f2b(fmaxf(hh[n][r], 0.f));
      }
    }

    // ---- LOGITS = H @ G2
    bf16x8 ah[4];
    #pragma unroll
    for (int kt = 0; kt < 4; kt++)
      ah[kt] = *(const bf16x8*)&tb[(lr*Dh + kt*32 + lg*8) ^ swtR];
    f32x4 lgt[8];
    #pragma unroll
    for (int n = 0; n < 8; n++) {
      f32x4 c = {0.f, 0.f, 0.f, 0.f};
      #pragma unroll
      for (int kt = 0; kt < 4; kt++)
        c = MFMA16(ah[kt], *(const bf16x8*)&wB[2][((n*16 + lr)*Dh + kt*32 + lg*8) ^ swz], c);
      lgt[n] = c;
    }

    // ---- softmax over 16 neighbors + agg = sum attn*(v+delta)
    #pragma unroll
    for (int n = 0; n < 8; n++) {
      f32x4 L = lgt[n];
      float m = fmaxf(fmaxf(L[0], L[1]), fmaxf(L[2], L[3]));
      m = fmaxf(m, __shfl_xor(m, 16));
      m = fmaxf(m, __shfl_xor(m, 32));
      float e0 = __expf(L[0]-m), e1 = __expf(L[1]-m);
      float e2 = __expf(L[2]-m), e3 = __expf(L[3]-m);
      float s = e0 + e1 + e2 + e3;
      s += __shfl_xor(s, 16);
      s += __shfl_xor(s, 32);
      float inv = 1.f / s;
      float ws;
      ws  = e0 * (bhi(kvr[n][0]) + dlt[n][0]);
      ws += e1 * (bhi(kvr[n][1]) + dlt[n][1]);
      ws += e2 * (bhi(kvr[n][2]) + dlt[n][2]);
      ws += e3 * (bhi(kvr[n][3]) + dlt[n][3]);
      ws *= inv;
      ws += __shfl_xor(ws, 16);
      ws += __shfl_xor(ws, 32);
      if (lg == 0) aggb[(size_t)p*Dh + n*16 + lr] = f2b(ws);
    }

    cur = nxt;
  }
}

// ---------------------------------------------------------------------------
// x += aggb @ Wo : [32768,128]@[128,128], f32 accumulate into x.
__global__ __launch_bounds__(256) void xupd_kernel(
    float* __restrict__ x, const unsigned short* __restrict__ aggb,
    const unsigned short* __restrict__ WoT) {
  int w = threadIdx.x >> 6, l = threadIdx.x & 63;
  int lr = l & 15, lg = l >> 4;
  int R = blockIdx.x * 64 + w * 16;
  bf16x8 a[4];
  #pragma unroll
  for (int kt = 0; kt < 4; kt++)
    a[kt] = *(const bf16x8*)&aggb[(size_t)(R + lr)*Dh + kt*32 + lg*8];
  #pragma unroll
  for (int n = 0; n < 8; n++) {
    f32x4 c = {0.f, 0.f, 0.f, 0.f};
    #pragma unroll
    for (int kt = 0; kt < 4; kt++)
      c = MFMA16(a[kt], *(const bf16x8*)&WoT[(n*16 + lr)*Dh + kt*32 + lg*8], c);
    #pragma unroll
    for (int r = 0; r < 4; r++)
      x[(size_t)(R + lg*4 + r)*Dh + n*16 + lr] += c[r];
  }
}

// ---------------------------------------------------------------------------
// Global max-pool + classifier head (f32)
__global__ __launch_bounds__(128) void pool_part_kernel(
    const float* __restrict__ x, float* __restrict__ part) {
  int b = blockIdx.y, chunk = blockIdx.x, d = threadIdx.x;
  const float* xb = x + ((size_t)b*NN + chunk*128) * Dh;
  float m = -FLT_MAX;
  for (int n = 0; n < 128; n++) m = fmaxf(m, xb[(size_t)n*Dh + d]);
  part[(b*32 + chunk)*Dh + d] = m;
}

__global__ __launch_bounds__(128) void head_kernel(
    const float* __restrict__ part, const float* __restrict__ W1,
    const float* __restrict__ W2, float* __restrict__ out) {
  int b = blockIdx.x, d = threadIdx.x;
  __shared__ float pooled[Dh], h[Dh];
  float m = -FLT_MAX;
  for (int c = 0; c < 32; c++) m = fmaxf(m, part[(b*32 + c)*Dh + d]);
  pooled[d] = m;
  __syncthreads();
  float acc = 0.f;
  for (int c = 0; c < Dh; c++) acc += pooled[c] * W1[c*Dh + d];
  h[d] = fmaxf(acc, 0.f);
  __syncthreads();
  if (d < 40) {
    float o = 0.f;
    for (int c = 0; c < Dh; c++) o += h[c] * W2[c*40 + d];
    out[b*40 + d] = o;
  }
}

// ---------------------------------------------------------------------------
extern "C" void kernel_launch(void* const* d_in, const int* in_sizes, int n_in,
                              void* d_out, int out_size, void* d_ws, size_t ws_size,
                              hipStream_t stream) {
  const float* features = (const float*)d_in[0];
  const float* pos      = (const float*)d_in[1];
  const float* W_embed  = (const float*)d_in[2];
  const float* Wq       = (const float*)d_in[3];
  const float* Wk       = (const float*)d_in[4];
  const float* Wv       = (const float*)d_in[5];
  const float* P1       = (const float*)d_in[6];
  const float* P2       = (const float*)d_in[7];
  const float* G1       = (const float*)d_in[8];
  const float* G2       = (const float*)d_in[9];
  const float* Wo       = (const float*)d_in[10];
  const float* Wc1      = (const float*)d_in[11];
  const float* Wc2      = (const float*)d_in[12];
  float* out = (float*)d_out;

  // workspace layout (16B-aligned slices)
  float* x = (float*)d_ws;                                     // NPTS*Dh f32 (16 MB)
  unsigned short* qb = (unsigned short*)(x + (size_t)NPTS*Dh); // NPTS*Dh bf16 (8 MB)
  unsigned* kvb = (unsigned*)(qb + (size_t)NPTS*Dh);           // NPTS*Dh u32 (16 MB)
  unsigned short* wT = (unsigned short*)(kvb + (size_t)NPTS*Dh); // 7*2*16384 bf16
  unsigned short* aggb = wT + 7*2*16384;                       // NPTS*Dh bf16 (8 MB)
  unsigned short* idxb = aggb + (size_t)NPTS*Dh;               // NPTS*KNN u16 (1 MB)

  // kNN partial indices (u16): aliased onto kvb (needs 8.4 MB of 16); dead before qkv.
  unsigned short* pidx = (unsigned short*)kvb;
  // pooled partials: aliased onto qb (dead after last fused layer).
  float* part = (float*)qb;

  unsigned short* QT  = wT + 0*32768;   // [2][128][128] each, transposed bf16
  unsigned short* KT  = wT + 1*32768;
  unsigned short* VT  = wT + 2*32768;
  unsigned short* P2T = wT + 3*32768;
  unsigned short* G1T = wT + 4*32768;
  unsigned short* G2T = wT + 5*32768;
  unsigned short* WoT = wT + 6*32768;

  knn_part_kernel<<<dim3(NN/256, NPART, BB), 256, 0, stream>>>(pos, pidx);
  knn_merge_kernel<<<NPTS/256, 256, 0, stream>>>(pos, pidx, idxb);

  wprep_all_kernel<<<dim3(64, 2, 7), 256, 0, stream>>>(Wq, Wk, Wv, P2, G1, G2, Wo, wT);
  embed_kernel<<<NPTS*Dh/256, 256, 0, stream>>>(features, W_embed, x);

  for (int l = 0; l < 2; l++) {
    qkv_kernel<<<NPTS/64, 256, 0, stream>>>(
        x, QT + l*16384, KT + l*16384, VT + l*16384, qb, kvb);
    fused_mega_kernel<<<256, 512, 0, stream>>>(
        qb, kvb, idxb, pos,
        P1 + l*3*Dh, P2T + l*16384, G1T + l*16384, G2T + l*16384, aggb);
    xupd_kernel<<<NPTS/64, 256, 0, stream>>>(x, aggb, WoT + l*16384);
  }

  pool_part_kernel<<<dim3(32, BB), 128, 0, stream>>>(x, part);
  head_kernel<<<BB, 128, 0, stream>>>(part, Wc1, Wc2, out);
}